// Round 5
// baseline (401.063 us; speedup 1.0000x reference)
//
#include <hip/hip_runtime.h>
#include <hip/hip_bf16.h>

typedef __hip_bfloat16 bf16;
typedef unsigned int uint;
typedef unsigned short ushort;
typedef __attribute__((ext_vector_type(8))) short short8;   // 8 bf16 = 4 VGPR
typedef __attribute__((ext_vector_type(4))) float float4v;  // MFMA acc

__device__ __forceinline__ float lo2f(uint v) { return __uint_as_float(v << 16); }
__device__ __forceinline__ float hi2f(uint v) { return __uint_as_float(v & 0xffff0000u); }
__device__ __forceinline__ ushort f2bu(float v) {
  union { bf16 h; ushort u; } x;
  x.h = __float2bfloat16(v);
  return x.u;
}
__device__ __forceinline__ uint packbf2(float a, float b) {
  return (uint)f2bu(a) | ((uint)f2bu(b) << 16);
}

#define BSH 8          // bucket shift: 256 nodes per bucket
#define NBK_MAX 391    // max buckets (txn side)

// ======================= fused weight transpose (6 jobs, 1 launch) ===========
struct TJob { const float* wl; const float* wr; ushort* dst; int da, k, ncol, boff; };
struct TJobs { TJob j[6]; };

__global__ void transpose6_kernel(TJobs js) {
  int b = blockIdx.x;
  int jj = 0;
#pragma unroll
  for (int t = 1; t < 6; ++t)
    if (b >= js.j[t].boff) jj = t;
  const TJob J = js.j[jj];
  int i = (b - J.boff) * 256 + threadIdx.x;
  if (i >= J.k * J.ncol) return;
  int k = i / J.ncol, c = i - k * J.ncol;
  const float* srcp = (k < J.da) ? (J.wl + (long long)k * J.ncol)
                                 : (J.wr + (long long)(k - J.da) * J.ncol);
  J.dst[(long long)c * J.k + k] = f2bu(srcp[c]);
}

// ======================= CSR build, two-level counting sort ==================
__global__ void bhist_kernel(const int* __restrict__ dA, int* __restrict__ cA, int nbkA,
                             const int* __restrict__ dB, int* __restrict__ cB, int nbkB,
                             int E, int chA) {
  __shared__ int h[NBK_MAX];
  int b = blockIdx.x;
  const int* dst; int* gc; int nbk;
  if (b < chA) { dst = dA; gc = cA; nbk = nbkA; }
  else         { b -= chA; dst = dB; gc = cB; nbk = nbkB; }
  for (int i = threadIdx.x; i < nbk; i += 256) h[i] = 0;
  __syncthreads();
  int e0 = b * 4096;
  for (int j = 0; j < 16; ++j) {
    int e = e0 + j * 256 + threadIdx.x;
    if (e < E) {
      uint B = (uint)dst[e] >> BSH;
      if (B < (uint)nbk) atomicAdd(&h[B], 1);
    }
  }
  __syncthreads();
  for (int i = threadIdx.x; i < nbk; i += 256)
    if (h[i]) atomicAdd(&gc[i], h[i]);
}

__global__ void bscan_kernel(const int* __restrict__ cA, int* __restrict__ oA,
                             int* __restrict__ uA, int nbkA,
                             const int* __restrict__ cB, int* __restrict__ oB,
                             int* __restrict__ uB, int nbkB) {
  __shared__ int s[512];
  const int* cnt; int* off; int* cur; int nbk;
  if (blockIdx.x == 0) { cnt = cA; off = oA; cur = uA; nbk = nbkA; }
  else                 { cnt = cB; off = oB; cur = uB; nbk = nbkB; }
  int t = threadIdx.x;
  int v = (t < nbk) ? cnt[t] : 0;
  s[t] = v;
  __syncthreads();
  for (int o = 1; o < 512; o <<= 1) {
    int x = (t >= o) ? s[t - o] : 0;
    __syncthreads();
    s[t] += x;
    __syncthreads();
  }
  if (t < nbk) { int ex = s[t] - v; off[t] = ex; cur[t] = ex; }
  if (t == nbk - 1) off[nbk] = s[t];
}

__global__ void multisplit_kernel(const int* __restrict__ sA, const int* __restrict__ dA,
                                  int* __restrict__ uA, uint2* __restrict__ seA, int nbkA,
                                  const int* __restrict__ sB, const int* __restrict__ dB,
                                  int* __restrict__ uB, uint2* __restrict__ seB, int nbkB,
                                  int E, int chA) {
  __shared__ int cnt[NBK_MAX];
  __shared__ int base[NBK_MAX];
  int b = blockIdx.x;
  const int *src, *dst; int* gcur; uint2* se; int nbk;
  if (b < chA) { src = sA; dst = dA; gcur = uA; se = seA; nbk = nbkA; }
  else         { b -= chA; src = sB; dst = dB; gcur = uB; se = seB; nbk = nbkB; }
  for (int i = threadIdx.x; i < nbk; i += 256) cnt[i] = 0;
  __syncthreads();
  int e0 = b * 4096;
  int mys[16], myd[16], myb[16], myr[16];
#pragma unroll
  for (int j = 0; j < 16; ++j) {
    int e = e0 + j * 256 + threadIdx.x;
    int s = 0, d = 0, bb = -1, r = 0;
    if (e < E) {
      s = src[e]; d = dst[e];
      uint B = (uint)d >> BSH;
      if (B < (uint)nbk) { bb = (int)B; r = atomicAdd(&cnt[bb], 1); }
    }
    mys[j] = s; myd[j] = d; myb[j] = bb; myr[j] = r;
  }
  __syncthreads();
  for (int i = threadIdx.x; i < nbk; i += 256) {
    int c = cnt[i];
    base[i] = c ? atomicAdd(&gcur[i], c) : 0;
  }
  __syncthreads();
#pragma unroll
  for (int j = 0; j < 16; ++j) {
    if (myb[j] >= 0) {
      uint2 v; v.x = (uint)mys[j]; v.y = (uint)myd[j];
      se[base[myb[j]] + myr[j]] = v;
    }
  }
}

__global__ void csr_fine_kernel(const uint2* __restrict__ seA, const int* __restrict__ boA,
                                int* __restrict__ offA, int* __restrict__ csrA, int nA, int nbkA,
                                const uint2* __restrict__ seB, const int* __restrict__ boB,
                                int* __restrict__ offB, int* __restrict__ csrB, int nB) {
  __shared__ int s[256];
  __shared__ int cur[256];
  int b = blockIdx.x;
  const uint2* se; const int* bo; int* off; int* csr; int n;
  if (b < nbkA) { se = seA; bo = boA; off = offA; csr = csrA; n = nA; }
  else          { b -= nbkA; se = seB; bo = boB; off = offB; csr = csrB; n = nB; }
  int t = threadIdx.x;
  int ebeg = bo[b], eend = bo[b + 1];
  cur[t] = 0;
  __syncthreads();
  for (int i = ebeg + t; i < eend; i += 256)
    atomicAdd(&cur[se[i].y & 255], 1);
  __syncthreads();
  int v = cur[t];
  s[t] = v;
  __syncthreads();
  for (int o = 1; o < 256; o <<= 1) {
    int x = (t >= o) ? s[t - o] : 0;
    __syncthreads();
    s[t] += x;
    __syncthreads();
  }
  int excl = s[t] - v;
  int node = b * 256 + t;
  if (node < n) off[node] = ebeg + excl;
  if (node == n - 1) off[n] = ebeg + excl + v;
  cur[t] = excl;
  __syncthreads();
  for (int i = ebeg + t; i < eend; i += 256) {
    uint2 e = se[i];
    int pos = ebeg + atomicAdd(&cur[e.y & 255], 1);
    csr[pos] = (int)e.x;
  }
}

// ======================= standalone pull (tc sides only) =====================
__device__ __forceinline__ void acc8(float* a, uint4 v) {
  a[0] += lo2f(v.x); a[1] += hi2f(v.x);
  a[2] += lo2f(v.y); a[3] += hi2f(v.y);
  a[4] += lo2f(v.z); a[5] += hi2f(v.z);
  a[6] += lo2f(v.w); a[7] += hi2f(v.w);
}
__device__ __forceinline__ void acc4(float* a, float4 v) {
  a[0] += v.x; a[1] += v.y; a[2] += v.z; a[3] += v.w;
}

template <int D, bool XBF>
__device__ __forceinline__ void pull_worker(
    const int* __restrict__ off, const int* __restrict__ csr,
    const void* __restrict__ x, bf16* __restrict__ mean, int n, int nsrc,
    int blk0) {
  constexpr int EPL = XBF ? 8 : 4;    // elems per lane (16B either way)
  constexpr int LPR = D / EPL;        // lanes per row
  constexpr int PAR = 64 / LPR;       // edges in parallel
  int node = ((int)blockIdx.x - blk0) * 4 + (threadIdx.x >> 6);
  if (node >= n) return;  // wave-uniform
  int lane = threadIdx.x & 63;
  int h = lane / LPR, col = lane % LPR;
  int beg = off[node], deg = off[node + 1] - beg;
  float inv = 1.0f / fmaxf((float)deg, 1.0f);
  float a[EPL];
#pragma unroll
  for (int e = 0; e < EPL; ++e) a[e] = 0.f;

  int i = h;
  for (; i + 3 * PAR < deg; i += 4 * PAR) {
    int s0 = csr[beg + i];
    int s1 = csr[beg + i + PAR];
    int s2 = csr[beg + i + 2 * PAR];
    int s3 = csr[beg + i + 3 * PAR];
    s0 = ((unsigned)s0 < (unsigned)nsrc) ? s0 : 0;
    s1 = ((unsigned)s1 < (unsigned)nsrc) ? s1 : 0;
    s2 = ((unsigned)s2 < (unsigned)nsrc) ? s2 : 0;
    s3 = ((unsigned)s3 < (unsigned)nsrc) ? s3 : 0;
    if (XBF) {
      uint4 v0 = ((const uint4*)x)[(long long)s0 * LPR + col];
      uint4 v1 = ((const uint4*)x)[(long long)s1 * LPR + col];
      uint4 v2 = ((const uint4*)x)[(long long)s2 * LPR + col];
      uint4 v3 = ((const uint4*)x)[(long long)s3 * LPR + col];
      acc8(a, v0); acc8(a, v1); acc8(a, v2); acc8(a, v3);
    } else {
      float4 v0 = ((const float4*)x)[(long long)s0 * LPR + col];
      float4 v1 = ((const float4*)x)[(long long)s1 * LPR + col];
      float4 v2 = ((const float4*)x)[(long long)s2 * LPR + col];
      float4 v3 = ((const float4*)x)[(long long)s3 * LPR + col];
      acc4(a, v0); acc4(a, v1); acc4(a, v2); acc4(a, v3);
    }
  }
  for (; i < deg; i += PAR) {
    int s = csr[beg + i];
    s = ((unsigned)s < (unsigned)nsrc) ? s : 0;
    if (XBF) {
      uint4 v = ((const uint4*)x)[(long long)s * LPR + col];
      acc8(a, v);
    } else {
      float4 v = ((const float4*)x)[(long long)s * LPR + col];
      acc4(a, v);
    }
  }

#pragma unroll
  for (int m = LPR; m < 64; m <<= 1) {
#pragma unroll
    for (int e = 0; e < EPL; ++e) a[e] += __shfl_xor(a[e], m);
  }
  if (h == 0) {
    if (XBF) {
      uint4 o4;
      o4.x = packbf2(a[0] * inv, a[1] * inv);
      o4.y = packbf2(a[2] * inv, a[3] * inv);
      o4.z = packbf2(a[4] * inv, a[5] * inv);
      o4.w = packbf2(a[6] * inv, a[7] * inv);
      ((uint4*)mean)[(long long)node * LPR + col] = o4;
    } else {
      uint2 o2;
      o2.x = packbf2(a[0] * inv, a[1] * inv);
      o2.y = packbf2(a[2] * inv, a[3] * inv);
      ((uint2*)mean)[(long long)node * LPR + col] = o2;
    }
  }
}

template <int D, bool XBF>
__global__ __launch_bounds__(256) void pull1_kernel(
    const int* __restrict__ off, const int* __restrict__ csr,
    const void* __restrict__ x, bf16* __restrict__ mean, int n, int nsrc) {
  pull_worker<D, XBF>(off, csr, x, mean, n, nsrc, 0);
}

// ======================= MFMA GEMM (no LDS, branch-free, MT row-tiles) =======
#define AT_BF16 0
#define AT_F32  1
template <int KT, int NCT, int K0T, int A0T, int A1T, bool OUTF32, int MT>
__global__ __launch_bounds__(256, 2) void gemm_kernel(
    const void* __restrict__ A0, int lda0,
    const void* __restrict__ A1, int lda1,
    const ushort* __restrict__ Wt, const float* __restrict__ bias,
    void* __restrict__ C, long long cbase, int ldc, int n, int relu) {
  constexpr int K = KT * 32;
  int tid = threadIdx.x;
  int wave = tid >> 6, lane = tid & 63;
  int p = lane & 15, q = lane >> 4;
  int rowbase = blockIdx.x * (64 * MT) + wave * (16 * MT);

  int rcl[MT];
#pragma unroll
  for (int m = 0; m < MT; ++m) rcl[m] = min(rowbase + m * 16 + p, n - 1);

  float4v acc[MT][NCT];
#pragma unroll
  for (int m = 0; m < MT; ++m)
#pragma unroll
    for (int t = 0; t < NCT; ++t) acc[m][t] = (float4v){0.f, 0.f, 0.f, 0.f};

#pragma unroll
  for (int kt = 0; kt < KT; ++kt) {
    const bool seg0 = (kt < K0T);
    const void* ab = seg0 ? A0 : A1;
    const int lda = seg0 ? lda0 : lda1;
    const int kof = (seg0 ? kt : (kt - K0T)) * 32;
    const int at = seg0 ? A0T : A1T;
    short8 af[MT];
#pragma unroll
    for (int m = 0; m < MT; ++m) {
      long long base = (long long)rcl[m] * lda + kof + q * 8;
      if (at == AT_BF16) {
        af[m] = *(const short8*)((const bf16*)ab + base);
      } else {
        const float* fb = (const float*)ab + base;
        float4 a = *(const float4*)fb;
        float4 b = *(const float4*)(fb + 4);
        short8 r;
        r[0] = (short)f2bu(a.x); r[1] = (short)f2bu(a.y);
        r[2] = (short)f2bu(a.z); r[3] = (short)f2bu(a.w);
        r[4] = (short)f2bu(b.x); r[5] = (short)f2bu(b.y);
        r[6] = (short)f2bu(b.z); r[7] = (short)f2bu(b.w);
        af[m] = r;
      }
    }
#pragma unroll
    for (int t = 0; t < NCT; ++t) {
      int c = t * 16 + p;
      short8 bfr = *(const short8*)(Wt + (long long)c * K + kt * 32 + q * 8);
#pragma unroll
      for (int m = 0; m < MT; ++m)
        acc[m][t] = __builtin_amdgcn_mfma_f32_16x16x32_bf16(af[m], bfr, acc[m][t], 0, 0, 0);
    }
  }

#pragma unroll
  for (int m = 0; m < MT; ++m) {
#pragma unroll
    for (int t = 0; t < NCT; ++t) {
      int c = t * 16 + p;
      float bv = bias[c];
#pragma unroll
      for (int r = 0; r < 4; ++r) {
        int row = rowbase + m * 16 + q * 4 + r;
        if (row < n) {
          float v = acc[m][t][r] + bv;
          if (relu) v = fmaxf(v, 0.f);
          long long idx = cbase + (long long)row * ldc + c;
          if (OUTF32) ((float*)C)[idx] = v;
          else        ((bf16*)C)[idx] = __float2bfloat16(v);
        }
      }
    }
  }
}

// ======================= layer-1 txn GEMM with fused ct-pull =================
// Each wave gathers its 64 rows' mean(x_cli) (deg~6, L2-resident 2.56MB table)
// into a wave-private 4KB LDS tile (bf16, XOR-swizzled), then runs the K=96
// GEMM reading A0 (kt=0) from LDS and A1 = x_txn (f32) from global.
// Removes the mean1_ct slab round-trip and overlaps gather with MFMA.
__global__ __launch_bounds__(256, 2) void gemm1a_fused_kernel(
    const int* __restrict__ off, const int* __restrict__ csr,
    const float* __restrict__ xg,    // x_cli [nsrc][32] (gather source)
    const float* __restrict__ A1,    // x_txn [n][64]
    const ushort* __restrict__ Wt,   // Wt1 [128][96]
    const float* __restrict__ bias,  // b1ct [128]
    bf16* __restrict__ C,            // h_txn [n][128]
    int n, int nsrc) {
  __shared__ __align__(16) char mls[16384];  // 4 waves x 4KB: [64 rows][64B]
  int tid = threadIdx.x, wave = tid >> 6, lane = tid & 63;
  int p = lane & 15, q = lane >> 4;
  int rowbase = blockIdx.x * 256 + wave * 64;
  char* wls = mls + wave * 4096;

  // ---- gather: mean of x_cli rows, 8 nodes in parallel (8 lanes/node) ----
  {
    int g = lane >> 3, li = lane & 7;  // lane li owns 16B f32 slice
    for (int it = 0; it < 8; ++it) {
      int lr = it * 8 + g;
      int node = min(rowbase + lr, n - 1);
      int beg = off[node], deg = off[node + 1] - beg;
      float inv = 1.0f / fmaxf((float)deg, 1.0f);
      float4 a0 = {0.f, 0.f, 0.f, 0.f}, a1 = {0.f, 0.f, 0.f, 0.f};
      int j = 0;
      for (; j + 1 < deg; j += 2) {
        int s0 = csr[beg + j], s1 = csr[beg + j + 1];
        s0 = ((unsigned)s0 < (unsigned)nsrc) ? s0 : 0;
        s1 = ((unsigned)s1 < (unsigned)nsrc) ? s1 : 0;
        float4 v0 = ((const float4*)xg)[(long long)s0 * 8 + li];
        float4 v1 = ((const float4*)xg)[(long long)s1 * 8 + li];
        a0.x += v0.x; a0.y += v0.y; a0.z += v0.z; a0.w += v0.w;
        a1.x += v1.x; a1.y += v1.y; a1.z += v1.z; a1.w += v1.w;
      }
      if (j < deg) {
        int s0 = csr[beg + j];
        s0 = ((unsigned)s0 < (unsigned)nsrc) ? s0 : 0;
        float4 v0 = ((const float4*)xg)[(long long)s0 * 8 + li];
        a0.x += v0.x; a0.y += v0.y; a0.z += v0.z; a0.w += v0.w;
      }
      uint2 u;
      u.x = packbf2((a0.x + a1.x) * inv, (a0.y + a1.y) * inv);
      u.y = packbf2((a0.z + a1.z) * inv, (a0.w + a1.w) * inv);
      *(uint2*)(wls + ((lr * 64 + li * 8) ^ ((lr & 3) << 4))) = u;
    }
  }
  // wave-private LDS, same-wave in-order => no barrier

  int rcl[4];
#pragma unroll
  for (int m = 0; m < 4; ++m) rcl[m] = min(rowbase + m * 16 + p, n - 1);

  float4v acc[4][8];
#pragma unroll
  for (int m = 0; m < 4; ++m)
#pragma unroll
    for (int t = 0; t < 8; ++t) acc[m][t] = (float4v){0.f, 0.f, 0.f, 0.f};

  const int sw1 = (p & 3) << 4;
#pragma unroll
  for (int kt = 0; kt < 3; ++kt) {
    short8 af[4];
#pragma unroll
    for (int m = 0; m < 4; ++m) {
      if (kt == 0) {
        af[m] = *(const short8*)(wls + ((((m * 16 + p) * 64) + q * 16) ^ sw1));
      } else {
        const float* fb = A1 + (long long)rcl[m] * 64 + (kt - 1) * 32 + q * 8;
        float4 a = *(const float4*)fb;
        float4 b = *(const float4*)(fb + 4);
        short8 r;
        r[0] = (short)f2bu(a.x); r[1] = (short)f2bu(a.y);
        r[2] = (short)f2bu(a.z); r[3] = (short)f2bu(a.w);
        r[4] = (short)f2bu(b.x); r[5] = (short)f2bu(b.y);
        r[6] = (short)f2bu(b.z); r[7] = (short)f2bu(b.w);
        af[m] = r;
      }
    }
#pragma unroll
    for (int t = 0; t < 8; ++t) {
      short8 bfr = *(const short8*)(Wt + (long long)(t * 16 + p) * 96 + kt * 32 + q * 8);
#pragma unroll
      for (int m = 0; m < 4; ++m)
        acc[m][t] = __builtin_amdgcn_mfma_f32_16x16x32_bf16(af[m], bfr, acc[m][t], 0, 0, 0);
    }
  }

#pragma unroll
  for (int m = 0; m < 4; ++m) {
#pragma unroll
    for (int t = 0; t < 8; ++t) {
      int c = t * 16 + p;
      float bv = bias[c];
#pragma unroll
      for (int r = 0; r < 4; ++r) {
        int row = rowbase + m * 16 + q * 4 + r;
        if (row < n)
          C[(long long)row * 128 + c] = __float2bfloat16(fmaxf(acc[m][t][r] + bv, 0.f));
      }
    }
  }
}

// ======================= fused L2-txn GEMM + decoder (+ct-pull) ==============
// Gather phase: each wave computes mean(h_cli) for its 64 rows directly into
// its 16KB LDS quadrant (bf16, XOR-swizzled) — the same region the z-tile
// reuses afterwards. Then: z = [mean|h_txn]@W2ct+b2 (swapped-operand MFMA,
// z^T in regs) -> global f32 + LDS bf16; d1 = relu(z@Wd1+bd1) (LDS);
// recon = d1@Wd2+bd2. All rounding points unchanged vs the unfused chain.
__global__ __launch_bounds__(256, 2) void gemm_fused_dec_kernel(
    const int* __restrict__ off, const int* __restrict__ csr,
    const bf16* __restrict__ xg,   // h_cli [nsrc][128] (gather source)
    const bf16* __restrict__ A1,   // h_txn [n][128]
    const ushort* __restrict__ W3, // Wt3 [128][256]
    const float* __restrict__ b2,  // [128]
    const ushort* __restrict__ W5, // Wt5 [64][128]
    const float* __restrict__ bd1v,// [64]
    const ushort* __restrict__ W6, // Wt6 [64][64]
    const float* __restrict__ bd2v,// [64]
    float* __restrict__ zout,      // d_out + ztxn_base, ld 128
    float* __restrict__ recon,     // d_out, ld 64
    int n, int nsrc) {
  __shared__ __align__(16) char zls[65536];  // 4 waves x 16KB, wave-private
  int tid = threadIdx.x;
  int wave = tid >> 6, lane = tid & 63;
  int p = lane & 15, q = lane >> 4;
  int rowbase = blockIdx.x * 256 + wave * 64;
  char* wls = zls + wave * 16384;
  const int sw = (p & 7) << 4;  // XOR swizzle

  // ---- gather: mean of h_cli rows, 4 nodes in parallel (16 lanes/node) ----
  {
    int g = lane >> 4, li = lane & 15;  // lane li owns 16B bf16 slice (8 elems)
    for (int it = 0; it < 16; ++it) {
      int lr = it * 4 + g;
      int node = min(rowbase + lr, n - 1);
      int beg = off[node], deg = off[node + 1] - beg;
      float inv = 1.0f / fmaxf((float)deg, 1.0f);
      float a0[8], a1[8];
#pragma unroll
      for (int e = 0; e < 8; ++e) { a0[e] = 0.f; a1[e] = 0.f; }
      int j = 0;
      for (; j + 1 < deg; j += 2) {
        int s0 = csr[beg + j], s1 = csr[beg + j + 1];
        s0 = ((unsigned)s0 < (unsigned)nsrc) ? s0 : 0;
        s1 = ((unsigned)s1 < (unsigned)nsrc) ? s1 : 0;
        uint4 v0 = ((const uint4*)xg)[(long long)s0 * 16 + li];
        uint4 v1 = ((const uint4*)xg)[(long long)s1 * 16 + li];
        acc8(a0, v0); acc8(a1, v1);
      }
      if (j < deg) {
        int s0 = csr[beg + j];
        s0 = ((unsigned)s0 < (unsigned)nsrc) ? s0 : 0;
        uint4 v0 = ((const uint4*)xg)[(long long)s0 * 16 + li];
        acc8(a0, v0);
      }
      uint4 u;
      u.x = packbf2((a0[0] + a1[0]) * inv, (a0[1] + a1[1]) * inv);
      u.y = packbf2((a0[2] + a1[2]) * inv, (a0[3] + a1[3]) * inv);
      u.z = packbf2((a0[4] + a1[4]) * inv, (a0[5] + a1[5]) * inv);
      u.w = packbf2((a0[6] + a1[6]) * inv, (a0[7] + a1[7]) * inv);
      *(uint4*)(wls + ((lr * 256 + li * 16) ^ ((lr & 7) << 4))) = u;
    }
  }
  // wave-private LDS, same-wave in-order => no barrier

  int rcl[4];
#pragma unroll
  for (int m = 0; m < 4; ++m) rcl[m] = min(rowbase + m * 16 + p, n - 1);

  // ---- stage 1: z accumulators (transposed layout) ----
  float4v accz[4][8];
#pragma unroll
  for (int m = 0; m < 4; ++m)
#pragma unroll
    for (int t = 0; t < 8; ++t) accz[m][t] = (float4v){0.f, 0.f, 0.f, 0.f};

#pragma unroll
  for (int kt = 0; kt < 8; ++kt) {
    short8 af[4];
#pragma unroll
    for (int m = 0; m < 4; ++m) {
      if (kt < 4) {  // A0 = mean tile in LDS
        af[m] = *(const short8*)(wls + ((((m * 16 + p) * 256) + kt * 64 + q * 16) ^ sw));
      } else {       // A1 = h_txn global
        af[m] = *(const short8*)(A1 + (long long)rcl[m] * 128 + (kt - 4) * 32 + q * 8);
      }
    }
#pragma unroll
    for (int t = 0; t < 8; ++t) {
      short8 bfr = *(const short8*)(W3 + (long long)(t * 16 + p) * 256 + kt * 32 + q * 8);
#pragma unroll
      for (int m = 0; m < 4; ++m)  // swapped: D[i=col][j=row] => z^T layout
        accz[m][t] = __builtin_amdgcn_mfma_f32_16x16x32_bf16(bfr, af[m], accz[m][t], 0, 0, 0);
    }
  }

  // epilogue: z -> global f32 (+bias), z -> LDS bf16 (overwrites mean tile;
  // same-wave in-order, all mean reads already issued above)
#pragma unroll
  for (int m = 0; m < 4; ++m) {
    int lr = m * 16 + p;
    int row = rowbase + lr;
#pragma unroll
    for (int t = 0; t < 8; ++t) {
      float4v bz = *(const float4v*)(b2 + t * 16 + q * 4);
      float4v v;
#pragma unroll
      for (int r = 0; r < 4; ++r) v[r] = accz[m][t][r] + bz[r];
      if (row < n)
        *(float4v*)(zout + (long long)row * 128 + t * 16 + q * 4) = v;
      uint2 u;
      u.x = packbf2(v[0], v[1]);
      u.y = packbf2(v[2], v[3]);
      *(uint2*)(wls + (((lr * 256 + t * 32 + q * 8)) ^ sw)) = u;
    }
  }
  __syncthreads();

  // ---- stage 2: d1 = relu(z @ Wd1 + bd1), K=128, 64 cols ----
  float4v accd[4][4];
#pragma unroll
  for (int m = 0; m < 4; ++m)
#pragma unroll
    for (int t = 0; t < 4; ++t) accd[m][t] = (float4v){0.f, 0.f, 0.f, 0.f};

#pragma unroll
  for (int kt2 = 0; kt2 < 4; ++kt2) {
    short8 zf[4];
#pragma unroll
    for (int m = 0; m < 4; ++m)
      zf[m] = *(const short8*)(wls + (((m * 16 + p) * 256 + kt2 * 64 + q * 16) ^ sw));
#pragma unroll
    for (int t2 = 0; t2 < 4; ++t2) {
      short8 wf = *(const short8*)(W5 + (long long)(t2 * 16 + p) * 128 + kt2 * 32 + q * 8);
#pragma unroll
      for (int m = 0; m < 4; ++m)
        accd[m][t2] = __builtin_amdgcn_mfma_f32_16x16x32_bf16(wf, zf[m], accd[m][t2], 0, 0, 0);
    }
  }
  __syncthreads();  // all z-reads done before overwriting region with d1

  // d1 (relu, bf16) -> LDS row-major [64][128B], same swizzle
#pragma unroll
  for (int m = 0; m < 4; ++m) {
    int lr = m * 16 + p;
#pragma unroll
    for (int t2 = 0; t2 < 4; ++t2) {
      float4v bb = *(const float4v*)(bd1v + t2 * 16 + q * 4);
      float4v v;
#pragma unroll
      for (int r = 0; r < 4; ++r) v[r] = fmaxf(accd[m][t2][r] + bb[r], 0.f);
      uint2 u;
      u.x = packbf2(v[0], v[1]);
      u.y = packbf2(v[2], v[3]);
      *(uint2*)(wls + (((lr * 128 + t2 * 32 + q * 8)) ^ sw)) = u;
    }
  }
  // same-wave LDS write->read is in-order; no barrier needed

  // ---- stage 3: recon = d1 @ Wd2 + bd2, K=64, 64 cols ----
  float4v accr[4][4];
#pragma unroll
  for (int m = 0; m < 4; ++m)
#pragma unroll
    for (int t = 0; t < 4; ++t) accr[m][t] = (float4v){0.f, 0.f, 0.f, 0.f};

#pragma unroll
  for (int kt3 = 0; kt3 < 2; ++kt3) {
    short8 df[4];
#pragma unroll
    for (int m = 0; m < 4; ++m)
      df[m] = *(const short8*)(wls + (((m * 16 + p) * 128 + kt3 * 64 + q * 16) ^ sw));
#pragma unroll
    for (int t3 = 0; t3 < 4; ++t3) {
      short8 wf = *(const short8*)(W6 + (long long)(t3 * 16 + p) * 64 + kt3 * 32 + q * 8);
#pragma unroll
      for (int m = 0; m < 4; ++m)
        accr[m][t3] = __builtin_amdgcn_mfma_f32_16x16x32_bf16(wf, df[m], accr[m][t3], 0, 0, 0);
    }
  }

#pragma unroll
  for (int m = 0; m < 4; ++m) {
    int row = rowbase + m * 16 + p;
    if (row < n) {
#pragma unroll
      for (int t3 = 0; t3 < 4; ++t3) {
        float4v bb = *(const float4v*)(bd2v + t3 * 16 + q * 4);
        float4v v;
#pragma unroll
        for (int r = 0; r < 4; ++r) v[r] = accr[m][t3][r] + bb[r];
        *(float4v*)(recon + (long long)row * 64 + t3 * 16 + q * 4) = v;
      }
    }
  }
}

// ======================= host ================================================
extern "C" void kernel_launch(void* const* d_in, const int* in_sizes, int n_in,
                              void* d_out, int out_size, void* d_ws,
                              size_t ws_size, hipStream_t stream) {
  const float* x_txn = (const float*)d_in[0];
  const float* x_cli = (const float*)d_in[1];
  const int* ct_src = (const int*)d_in[2];
  const int* ct_dst = (const int*)d_in[3];
  const int* tc_src = (const int*)d_in[4];
  const int* tc_dst = (const int*)d_in[5];
  const float* W1ctl = (const float*)d_in[6];
  const float* b1ct  = (const float*)d_in[7];
  const float* W1ctr = (const float*)d_in[8];
  const float* W1tcl = (const float*)d_in[9];
  const float* b1tc  = (const float*)d_in[10];
  const float* W1tcr = (const float*)d_in[11];
  const float* W2ctl = (const float*)d_in[12];
  const float* b2ct  = (const float*)d_in[13];
  const float* W2ctr = (const float*)d_in[14];
  const float* W2tcl = (const float*)d_in[15];
  const float* b2tc  = (const float*)d_in[16];
  const float* W2tcr = (const float*)d_in[17];
  const float* Wd1   = (const float*)d_in[18];
  const float* bd1   = (const float*)d_in[19];
  const float* Wd2   = (const float*)d_in[20];
  const float* bd2   = (const float*)d_in[21];

  const int E = in_sizes[2];  // 600000
  const int NT = 100000, NC = 20000;
  const int NBK_CT = (NT + 255) >> 8;  // 391
  const int NBK_TC = (NC + 255) >> 8;  // 79

  // ---- workspace carve ----
  size_t o = 0;
  auto carve = [&](size_t bytes) {
    void* p = (char*)d_ws + o;
    o = (o + bytes + 255) & ~(size_t)255;
    return p;
  };
  int* bcnt_ct = (int*)carve((size_t)NBK_CT * 4);       // zeroed
  int* bcnt_tc = (int*)carve((size_t)NBK_TC * 4);       // zeroed (same page run)
  size_t zero_bytes = o;
  int* boff_ct = (int*)carve((size_t)(NBK_CT + 1) * 4);
  int* boff_tc = (int*)carve((size_t)(NBK_TC + 1) * 4);
  int* bcur_ct = (int*)carve((size_t)NBK_CT * 4);
  int* bcur_tc = (int*)carve((size_t)NBK_TC * 4);
  uint2* se_ct = (uint2*)carve((size_t)E * 8);
  uint2* se_tc = (uint2*)carve((size_t)E * 8);
  int* off_ct = (int*)carve((size_t)(NT + 1) * 4);
  int* off_tc = (int*)carve((size_t)(NC + 1) * 4);
  int* csr_ct = (int*)carve((size_t)E * 4);
  int* csr_tc = (int*)carve((size_t)E * 4);
  ushort* Wt1 = (ushort*)carve((size_t)96 * 128 * 2);
  ushort* Wt2 = (ushort*)carve((size_t)96 * 128 * 2);
  ushort* Wt3 = (ushort*)carve((size_t)256 * 128 * 2);
  ushort* Wt4 = (ushort*)carve((size_t)256 * 128 * 2);
  ushort* Wt5 = (ushort*)carve((size_t)128 * 64 * 2);
  ushort* Wt6 = (ushort*)carve((size_t)64 * 64 * 2);
  bf16* mean1_tc = (bf16*)carve((size_t)NC * 64 * 2);
  bf16* h_txn    = (bf16*)carve((size_t)NT * 128 * 2);
  bf16* h_cli    = (bf16*)carve((size_t)NC * 128 * 2);
  bf16* mean2_tc = (bf16*)carve((size_t)NC * 128 * 2);
  (void)ws_size;

  hipMemsetAsync(d_ws, 0, zero_bytes, stream);

  const int tb = 256;
  const int CH = (E + 4095) / 4096;  // 147 chunks per edge type

  // ---- fused weight transposes (1 launch) ----
  {
    TJobs js;
    auto blocks = [](int k, int ncol) { return (k * ncol + 255) / 256; };
    int boff = 0;
    auto setj = [&](int idx, const float* wl, const float* wr, ushort* dst,
                    int da, int k, int ncol) {
      js.j[idx] = TJob{wl, wr, dst, da, k, ncol, boff};
      boff += blocks(k, ncol);
    };
    setj(0, W1ctl, W1ctr, Wt1, 32, 96, 128);
    setj(1, W1tcl, W1tcr, Wt2, 64, 96, 128);
    setj(2, W2ctl, W2ctr, Wt3, 128, 256, 128);
    setj(3, W2tcl, W2tcr, Wt4, 128, 256, 128);
    setj(4, Wd1, Wd1, Wt5, 128, 128, 64);
    setj(5, Wd2, Wd2, Wt6, 64, 64, 64);
    transpose6_kernel<<<boff, tb, 0, stream>>>(js);
  }

  // ---- CSR build: two-level counting sort (both edge types fused) ----
  bhist_kernel<<<2 * CH, tb, 0, stream>>>(ct_dst, bcnt_ct, NBK_CT,
                                          tc_dst, bcnt_tc, NBK_TC, E, CH);
  bscan_kernel<<<2, 512, 0, stream>>>(bcnt_ct, boff_ct, bcur_ct, NBK_CT,
                                      bcnt_tc, boff_tc, bcur_tc, NBK_TC);
  multisplit_kernel<<<2 * CH, tb, 0, stream>>>(
      ct_src, ct_dst, bcur_ct, se_ct, NBK_CT,
      tc_src, tc_dst, bcur_tc, se_tc, NBK_TC, E, CH);
  csr_fine_kernel<<<NBK_CT + NBK_TC, tb, 0, stream>>>(
      se_ct, boff_ct, off_ct, csr_ct, NT, NBK_CT,
      se_tc, boff_tc, off_tc, csr_tc, NC);

  const int gNT = (NT + 255) / 256;  // 391 blocks (256 rows each)

  // ---- layer 1: tc pull (standalone), then txn GEMM with fused ct-pull ----
  pull1_kernel<64, false><<<(NC + 3) / 4, tb, 0, stream>>>(
      off_tc, csr_tc, x_txn, mean1_tc, NC, NT);

  gemm1a_fused_kernel<<<gNT, tb, 0, stream>>>(
      off_ct, csr_ct, x_cli, x_txn, Wt1, b1ct, h_txn, NT, NC);

  gemm_kernel<3, 8, 2, AT_BF16, AT_F32, false, 1><<<(NC + 63) / 64, tb, 0, stream>>>(
      mean1_tc, 64, x_cli, 32, Wt2, b1tc, h_cli, 0, 128, NC, 1);

  // ---- layer 2: tc pull (standalone) ----
  pull1_kernel<128, true><<<(NC + 3) / 4, tb, 0, stream>>>(
      off_tc, csr_tc, h_txn, mean2_tc, NC, NT);

  float* out = (float*)d_out;
  const long long ztxn_base = (long long)NT * 64;
  const long long zcli_base = ztxn_base + (long long)NT * 128;

  // ---- fused: ct-pull + z_txn + decoder ----
  gemm_fused_dec_kernel<<<gNT, tb, 0, stream>>>(
      off_ct, csr_ct, h_cli, h_txn, Wt3, b2ct, Wt5, bd1, Wt6, bd2,
      out + ztxn_base, out, NT, NC);

  gemm_kernel<8, 8, 4, AT_BF16, AT_BF16, true, 1><<<(NC + 63) / 64, tb, 0, stream>>>(
      mean2_tc, 128, h_cli, 128, Wt4, b2tc, out, zcli_base, 128, NC, 0);
}

// Round 6
// 367.033 us; speedup vs baseline: 1.0927x; 1.0927x over previous
//
#include <hip/hip_runtime.h>
#include <hip/hip_bf16.h>

typedef __hip_bfloat16 bf16;
typedef unsigned int uint;
typedef unsigned short ushort;
typedef __attribute__((ext_vector_type(8))) short short8;   // 8 bf16 = 4 VGPR
typedef __attribute__((ext_vector_type(4))) float float4v;  // MFMA acc

__device__ __forceinline__ float lo2f(uint v) { return __uint_as_float(v << 16); }
__device__ __forceinline__ float hi2f(uint v) { return __uint_as_float(v & 0xffff0000u); }
__device__ __forceinline__ ushort f2bu(float v) {
  union { bf16 h; ushort u; } x;
  x.h = __float2bfloat16(v);
  return x.u;
}
__device__ __forceinline__ uint packbf2(float a, float b) {
  return (uint)f2bu(a) | ((uint)f2bu(b) << 16);
}

#define BSH 8          // bucket shift: 256 nodes per bucket
#define NBK_MAX 391    // max buckets (txn side)

// ======================= fused weight transpose (6 jobs, 1 launch) ===========
struct TJob { const float* wl; const float* wr; ushort* dst; int da, k, ncol, boff; };
struct TJobs { TJob j[6]; };

__global__ void transpose6_kernel(TJobs js) {
  int b = blockIdx.x;
  int jj = 0;
#pragma unroll
  for (int t = 1; t < 6; ++t)
    if (b >= js.j[t].boff) jj = t;
  const TJob J = js.j[jj];
  int i = (b - J.boff) * 256 + threadIdx.x;
  if (i >= J.k * J.ncol) return;
  int k = i / J.ncol, c = i - k * J.ncol;
  const float* srcp = (k < J.da) ? (J.wl + (long long)k * J.ncol)
                                 : (J.wr + (long long)(k - J.da) * J.ncol);
  J.dst[(long long)c * J.k + k] = f2bu(srcp[c]);
}

// ======================= CSR build, two-level counting sort ==================
__global__ void bhist_kernel(const int* __restrict__ dA, int* __restrict__ cA, int nbkA,
                             const int* __restrict__ dB, int* __restrict__ cB, int nbkB,
                             int E, int chA) {
  __shared__ int h[NBK_MAX];
  int b = blockIdx.x;
  const int* dst; int* gc; int nbk;
  if (b < chA) { dst = dA; gc = cA; nbk = nbkA; }
  else         { b -= chA; dst = dB; gc = cB; nbk = nbkB; }
  for (int i = threadIdx.x; i < nbk; i += 256) h[i] = 0;
  __syncthreads();
  int e0 = b * 4096;
  for (int j = 0; j < 16; ++j) {
    int e = e0 + j * 256 + threadIdx.x;
    if (e < E) {
      uint B = (uint)dst[e] >> BSH;
      if (B < (uint)nbk) atomicAdd(&h[B], 1);
    }
  }
  __syncthreads();
  for (int i = threadIdx.x; i < nbk; i += 256)
    if (h[i]) atomicAdd(&gc[i], h[i]);
}

__global__ void bscan_kernel(const int* __restrict__ cA, int* __restrict__ oA,
                             int* __restrict__ uA, int nbkA,
                             const int* __restrict__ cB, int* __restrict__ oB,
                             int* __restrict__ uB, int nbkB) {
  __shared__ int s[512];
  const int* cnt; int* off; int* cur; int nbk;
  if (blockIdx.x == 0) { cnt = cA; off = oA; cur = uA; nbk = nbkA; }
  else                 { cnt = cB; off = oB; cur = uB; nbk = nbkB; }
  int t = threadIdx.x;
  int v = (t < nbk) ? cnt[t] : 0;
  s[t] = v;
  __syncthreads();
  for (int o = 1; o < 512; o <<= 1) {
    int x = (t >= o) ? s[t - o] : 0;
    __syncthreads();
    s[t] += x;
    __syncthreads();
  }
  if (t < nbk) { int ex = s[t] - v; off[t] = ex; cur[t] = ex; }
  if (t == nbk - 1) off[nbk] = s[t];
}

__global__ void multisplit_kernel(const int* __restrict__ sA, const int* __restrict__ dA,
                                  int* __restrict__ uA, uint2* __restrict__ seA, int nbkA,
                                  const int* __restrict__ sB, const int* __restrict__ dB,
                                  int* __restrict__ uB, uint2* __restrict__ seB, int nbkB,
                                  int E, int chA) {
  __shared__ int cnt[NBK_MAX];
  __shared__ int base[NBK_MAX];
  int b = blockIdx.x;
  const int *src, *dst; int* gcur; uint2* se; int nbk;
  if (b < chA) { src = sA; dst = dA; gcur = uA; se = seA; nbk = nbkA; }
  else         { b -= chA; src = sB; dst = dB; gcur = uB; se = seB; nbk = nbkB; }
  for (int i = threadIdx.x; i < nbk; i += 256) cnt[i] = 0;
  __syncthreads();
  int e0 = b * 4096;
  int mys[16], myd[16], myb[16], myr[16];
#pragma unroll
  for (int j = 0; j < 16; ++j) {
    int e = e0 + j * 256 + threadIdx.x;
    int s = 0, d = 0, bb = -1, r = 0;
    if (e < E) {
      s = src[e]; d = dst[e];
      uint B = (uint)d >> BSH;
      if (B < (uint)nbk) { bb = (int)B; r = atomicAdd(&cnt[bb], 1); }
    }
    mys[j] = s; myd[j] = d; myb[j] = bb; myr[j] = r;
  }
  __syncthreads();
  for (int i = threadIdx.x; i < nbk; i += 256) {
    int c = cnt[i];
    base[i] = c ? atomicAdd(&gcur[i], c) : 0;
  }
  __syncthreads();
#pragma unroll
  for (int j = 0; j < 16; ++j) {
    if (myb[j] >= 0) {
      uint2 v; v.x = (uint)mys[j]; v.y = (uint)myd[j];
      se[base[myb[j]] + myr[j]] = v;
    }
  }
}

__global__ void csr_fine_kernel(const uint2* __restrict__ seA, const int* __restrict__ boA,
                                int* __restrict__ offA, int* __restrict__ csrA, int nA, int nbkA,
                                const uint2* __restrict__ seB, const int* __restrict__ boB,
                                int* __restrict__ offB, int* __restrict__ csrB, int nB) {
  __shared__ int s[256];
  __shared__ int cur[256];
  int b = blockIdx.x;
  const uint2* se; const int* bo; int* off; int* csr; int n;
  if (b < nbkA) { se = seA; bo = boA; off = offA; csr = csrA; n = nA; }
  else          { b -= nbkA; se = seB; bo = boB; off = offB; csr = csrB; n = nB; }
  int t = threadIdx.x;
  int ebeg = bo[b], eend = bo[b + 1];
  cur[t] = 0;
  __syncthreads();
  for (int i = ebeg + t; i < eend; i += 256)
    atomicAdd(&cur[se[i].y & 255], 1);
  __syncthreads();
  int v = cur[t];
  s[t] = v;
  __syncthreads();
  for (int o = 1; o < 256; o <<= 1) {
    int x = (t >= o) ? s[t - o] : 0;
    __syncthreads();
    s[t] += x;
    __syncthreads();
  }
  int excl = s[t] - v;
  int node = b * 256 + t;
  if (node < n) off[node] = ebeg + excl;
  if (node == n - 1) off[n] = ebeg + excl + v;
  cur[t] = excl;
  __syncthreads();
  for (int i = ebeg + t; i < eend; i += 256) {
    uint2 e = se[i];
    int pos = ebeg + atomicAdd(&cur[e.y & 255], 1);
    csr[pos] = (int)e.x;
  }
}

// ======================= pull aggregation (mean, bf16 out) — R3-validated ====
// High-occupancy dedicated gather kernels (R4 lesson: gathers need waves in
// flight; never fuse them into low-block-count GEMM kernels).
__device__ __forceinline__ void acc8(float* a, uint4 v) {
  a[0] += lo2f(v.x); a[1] += hi2f(v.x);
  a[2] += lo2f(v.y); a[3] += hi2f(v.y);
  a[4] += lo2f(v.z); a[5] += hi2f(v.z);
  a[6] += lo2f(v.w); a[7] += hi2f(v.w);
}
__device__ __forceinline__ void acc4(float* a, float4 v) {
  a[0] += v.x; a[1] += v.y; a[2] += v.z; a[3] += v.w;
}

template <int D, bool XBF>
__device__ __forceinline__ void pull_worker(
    const int* __restrict__ off, const int* __restrict__ csr,
    const void* __restrict__ x, bf16* __restrict__ mean, int n, int nsrc,
    int blk0) {
  constexpr int EPL = XBF ? 8 : 4;    // elems per lane (16B either way)
  constexpr int LPR = D / EPL;        // lanes per row
  constexpr int PAR = 64 / LPR;       // edges in parallel
  int node = ((int)blockIdx.x - blk0) * 4 + (threadIdx.x >> 6);
  if (node >= n) return;  // wave-uniform
  int lane = threadIdx.x & 63;
  int h = lane / LPR, col = lane % LPR;
  int beg = off[node], deg = off[node + 1] - beg;
  float inv = 1.0f / fmaxf((float)deg, 1.0f);
  float a[EPL];
#pragma unroll
  for (int e = 0; e < EPL; ++e) a[e] = 0.f;

  int i = h;
  for (; i + 3 * PAR < deg; i += 4 * PAR) {
    int s0 = csr[beg + i];
    int s1 = csr[beg + i + PAR];
    int s2 = csr[beg + i + 2 * PAR];
    int s3 = csr[beg + i + 3 * PAR];
    s0 = ((unsigned)s0 < (unsigned)nsrc) ? s0 : 0;
    s1 = ((unsigned)s1 < (unsigned)nsrc) ? s1 : 0;
    s2 = ((unsigned)s2 < (unsigned)nsrc) ? s2 : 0;
    s3 = ((unsigned)s3 < (unsigned)nsrc) ? s3 : 0;
    if (XBF) {
      uint4 v0 = ((const uint4*)x)[(long long)s0 * LPR + col];
      uint4 v1 = ((const uint4*)x)[(long long)s1 * LPR + col];
      uint4 v2 = ((const uint4*)x)[(long long)s2 * LPR + col];
      uint4 v3 = ((const uint4*)x)[(long long)s3 * LPR + col];
      acc8(a, v0); acc8(a, v1); acc8(a, v2); acc8(a, v3);
    } else {
      float4 v0 = ((const float4*)x)[(long long)s0 * LPR + col];
      float4 v1 = ((const float4*)x)[(long long)s1 * LPR + col];
      float4 v2 = ((const float4*)x)[(long long)s2 * LPR + col];
      float4 v3 = ((const float4*)x)[(long long)s3 * LPR + col];
      acc4(a, v0); acc4(a, v1); acc4(a, v2); acc4(a, v3);
    }
  }
  for (; i < deg; i += PAR) {
    int s = csr[beg + i];
    s = ((unsigned)s < (unsigned)nsrc) ? s : 0;
    if (XBF) {
      uint4 v = ((const uint4*)x)[(long long)s * LPR + col];
      acc8(a, v);
    } else {
      float4 v = ((const float4*)x)[(long long)s * LPR + col];
      acc4(a, v);
    }
  }

#pragma unroll
  for (int m = LPR; m < 64; m <<= 1) {
#pragma unroll
    for (int e = 0; e < EPL; ++e) a[e] += __shfl_xor(a[e], m);
  }
  if (h == 0) {
    if (XBF) {
      uint4 o4;
      o4.x = packbf2(a[0] * inv, a[1] * inv);
      o4.y = packbf2(a[2] * inv, a[3] * inv);
      o4.z = packbf2(a[4] * inv, a[5] * inv);
      o4.w = packbf2(a[6] * inv, a[7] * inv);
      ((uint4*)mean)[(long long)node * LPR + col] = o4;
    } else {
      uint2 o2;
      o2.x = packbf2(a[0] * inv, a[1] * inv);
      o2.y = packbf2(a[2] * inv, a[3] * inv);
      ((uint2*)mean)[(long long)node * LPR + col] = o2;
    }
  }
}

template <int DA, bool XA, int DB, bool XB>
__global__ __launch_bounds__(256) void pull2_kernel(
    const int* __restrict__ offA, const int* __restrict__ csrA,
    const void* __restrict__ xA, bf16* __restrict__ meanA, int nA, int nsrcA,
    const int* __restrict__ offB, const int* __restrict__ csrB,
    const void* __restrict__ xB, bf16* __restrict__ meanB, int nB, int nsrcB,
    int nblkA) {
  if ((int)blockIdx.x < nblkA)
    pull_worker<DA, XA>(offA, csrA, xA, meanA, nA, nsrcA, 0);
  else
    pull_worker<DB, XB>(offB, csrB, xB, meanB, nB, nsrcB, nblkA);
}

// ======================= MFMA GEMM worker (no LDS, MT row-tiles) =============
#define AT_BF16 0
#define AT_F32  1
template <int KT, int NCT, int K0T, int A0T, int A1T, bool OUTF32, int MT>
__device__ __forceinline__ void gemm_worker(
    const void* __restrict__ A0, int lda0,
    const void* __restrict__ A1, int lda1,
    const ushort* __restrict__ Wt, const float* __restrict__ bias,
    void* __restrict__ C, long long cbase, int ldc, int n, int relu, int blk0) {
  constexpr int K = KT * 32;
  int tid = threadIdx.x;
  int wave = tid >> 6, lane = tid & 63;
  int p = lane & 15, q = lane >> 4;
  int rowbase = ((int)blockIdx.x - blk0) * (64 * MT) + wave * (16 * MT);

  int rcl[MT];
#pragma unroll
  for (int m = 0; m < MT; ++m) rcl[m] = min(rowbase + m * 16 + p, n - 1);

  float4v acc[MT][NCT];
#pragma unroll
  for (int m = 0; m < MT; ++m)
#pragma unroll
    for (int t = 0; t < NCT; ++t) acc[m][t] = (float4v){0.f, 0.f, 0.f, 0.f};

#pragma unroll
  for (int kt = 0; kt < KT; ++kt) {
    const bool seg0 = (kt < K0T);
    const void* ab = seg0 ? A0 : A1;
    const int lda = seg0 ? lda0 : lda1;
    const int kof = (seg0 ? kt : (kt - K0T)) * 32;
    const int at = seg0 ? A0T : A1T;
    short8 af[MT];
#pragma unroll
    for (int m = 0; m < MT; ++m) {
      long long base = (long long)rcl[m] * lda + kof + q * 8;
      if (at == AT_BF16) {
        af[m] = *(const short8*)((const bf16*)ab + base);
      } else {
        const float* fb = (const float*)ab + base;
        float4 a = *(const float4*)fb;
        float4 b = *(const float4*)(fb + 4);
        short8 r;
        r[0] = (short)f2bu(a.x); r[1] = (short)f2bu(a.y);
        r[2] = (short)f2bu(a.z); r[3] = (short)f2bu(a.w);
        r[4] = (short)f2bu(b.x); r[5] = (short)f2bu(b.y);
        r[6] = (short)f2bu(b.z); r[7] = (short)f2bu(b.w);
        af[m] = r;
      }
    }
#pragma unroll
    for (int t = 0; t < NCT; ++t) {
      int c = t * 16 + p;
      short8 bfr = *(const short8*)(Wt + (long long)c * K + kt * 32 + q * 8);
#pragma unroll
      for (int m = 0; m < MT; ++m)
        acc[m][t] = __builtin_amdgcn_mfma_f32_16x16x32_bf16(af[m], bfr, acc[m][t], 0, 0, 0);
    }
  }

#pragma unroll
  for (int m = 0; m < MT; ++m) {
#pragma unroll
    for (int t = 0; t < NCT; ++t) {
      int c = t * 16 + p;
      float bv = bias[c];
#pragma unroll
      for (int r = 0; r < 4; ++r) {
        int row = rowbase + m * 16 + q * 4 + r;
        if (row < n) {
          float v = acc[m][t][r] + bv;
          if (relu) v = fmaxf(v, 0.f);
          long long idx = cbase + (long long)row * ldc + c;
          if (OUTF32) ((float*)C)[idx] = v;
          else        ((bf16*)C)[idx] = __float2bfloat16(v);
        }
      }
    }
  }
}

// ======================= layer-1: both GEMMs in one launch ===================
// gemm1a (391 blocks, MT=4) + gemm1b (313 blocks, MT=1): both ready after
// pull2-L1; fused block-range launch fills 2.75 blocks/CU vs 1.5 standalone
// and removes one launch gap. Numerics identical to separate launches.
__global__ __launch_bounds__(256, 2) void gemm_l1_kernel(
    const bf16* __restrict__ m1ct, const float* __restrict__ xtxn,
    const ushort* __restrict__ Wt1, const float* __restrict__ b1ct,
    bf16* __restrict__ htxn,
    const bf16* __restrict__ m1tc, const float* __restrict__ xcli,
    const ushort* __restrict__ Wt2, const float* __restrict__ b1tc,
    bf16* __restrict__ hcli, int nT, int nC, int nblkA) {
  if ((int)blockIdx.x < nblkA)
    gemm_worker<3, 8, 1, AT_BF16, AT_F32, false, 4>(
        m1ct, 32, xtxn, 64, Wt1, b1ct, htxn, 0, 128, nT, 1, 0);
  else
    gemm_worker<3, 8, 2, AT_BF16, AT_F32, false, 1>(
        m1tc, 64, xcli, 32, Wt2, b1tc, hcli, 0, 128, nC, 1, nblkA);
}

// ======================= fused L2-txn GEMM + decoder worker (R3-validated) ===
__device__ __forceinline__ void dec_worker(
    char* zls,
    const bf16* __restrict__ A0,   // mean2_ct [n][128]
    const bf16* __restrict__ A1,   // h_txn    [n][128]
    const ushort* __restrict__ W3, // Wt3 [128][256]
    const float* __restrict__ b2,  // [128]
    const ushort* __restrict__ W5, // Wt5 [64][128]
    const float* __restrict__ bd1v,// [64]
    const ushort* __restrict__ W6, // Wt6 [64][64]
    const float* __restrict__ bd2v,// [64]
    float* __restrict__ zout,      // d_out + ztxn_base, ld 128
    float* __restrict__ recon,     // d_out, ld 64
    int n) {
  int tid = threadIdx.x;
  int wave = tid >> 6, lane = tid & 63;
  int p = lane & 15, q = lane >> 4;
  int rowbase = blockIdx.x * 256 + wave * 64;
  char* wls = zls + wave * 16384;
  const int sw = (p & 7) << 4;  // XOR swizzle

  int rcl[4];
#pragma unroll
  for (int m = 0; m < 4; ++m) rcl[m] = min(rowbase + m * 16 + p, n - 1);

  // ---- stage 1: z accumulators (transposed layout via swapped operands) ----
  float4v accz[4][8];
#pragma unroll
  for (int m = 0; m < 4; ++m)
#pragma unroll
    for (int t = 0; t < 8; ++t) accz[m][t] = (float4v){0.f, 0.f, 0.f, 0.f};

#pragma unroll
  for (int kt = 0; kt < 8; ++kt) {
    const bf16* ab = (kt < 4) ? A0 : A1;
    const int kof = (kt & 3) * 32;
    short8 af[4];
#pragma unroll
    for (int m = 0; m < 4; ++m)
      af[m] = *(const short8*)(ab + (long long)rcl[m] * 128 + kof + q * 8);
#pragma unroll
    for (int t = 0; t < 8; ++t) {
      short8 bfr = *(const short8*)(W3 + (long long)(t * 16 + p) * 256 + kt * 32 + q * 8);
#pragma unroll
      for (int m = 0; m < 4; ++m)
        accz[m][t] = __builtin_amdgcn_mfma_f32_16x16x32_bf16(bfr, af[m], accz[m][t], 0, 0, 0);
    }
  }

  // epilogue: z -> global f32 (+bias), z -> LDS bf16 (row-major [64][256B], swz)
#pragma unroll
  for (int m = 0; m < 4; ++m) {
    int lr = m * 16 + p;
    int row = rowbase + lr;
#pragma unroll
    for (int t = 0; t < 8; ++t) {
      float4v bz = *(const float4v*)(b2 + t * 16 + q * 4);
      float4v v;
#pragma unroll
      for (int r = 0; r < 4; ++r) v[r] = accz[m][t][r] + bz[r];
      if (row < n)
        *(float4v*)(zout + (long long)row * 128 + t * 16 + q * 4) = v;
      uint2 u;
      u.x = packbf2(v[0], v[1]);
      u.y = packbf2(v[2], v[3]);
      *(uint2*)(wls + (((lr * 256 + t * 32 + q * 8)) ^ sw)) = u;
    }
  }
  __syncthreads();

  // ---- stage 2: d1 = relu(z @ Wd1 + bd1), K=128, 64 cols ----
  float4v accd[4][4];
#pragma unroll
  for (int m = 0; m < 4; ++m)
#pragma unroll
    for (int t = 0; t < 4; ++t) accd[m][t] = (float4v){0.f, 0.f, 0.f, 0.f};

#pragma unroll
  for (int kt2 = 0; kt2 < 4; ++kt2) {
    short8 zf[4];
#pragma unroll
    for (int m = 0; m < 4; ++m)
      zf[m] = *(const short8*)(wls + (((m * 16 + p) * 256 + kt2 * 64 + q * 16) ^ sw));
#pragma unroll
    for (int t2 = 0; t2 < 4; ++t2) {
      short8 wf = *(const short8*)(W5 + (long long)(t2 * 16 + p) * 128 + kt2 * 32 + q * 8);
#pragma unroll
      for (int m = 0; m < 4; ++m)
        accd[m][t2] = __builtin_amdgcn_mfma_f32_16x16x32_bf16(wf, zf[m], accd[m][t2], 0, 0, 0);
    }
  }
  __syncthreads();  // all z-reads done before overwriting region with d1

  // d1 (relu, bf16) -> LDS row-major [64][128B], same swizzle
#pragma unroll
  for (int m = 0; m < 4; ++m) {
    int lr = m * 16 + p;
#pragma unroll
    for (int t2 = 0; t2 < 4; ++t2) {
      float4v bb = *(const float4v*)(bd1v + t2 * 16 + q * 4);
      float4v v;
#pragma unroll
      for (int r = 0; r < 4; ++r) v[r] = fmaxf(accd[m][t2][r] + bb[r], 0.f);
      uint2 u;
      u.x = packbf2(v[0], v[1]);
      u.y = packbf2(v[2], v[3]);
      *(uint2*)(wls + (((lr * 128 + t2 * 32 + q * 8)) ^ sw)) = u;
    }
  }
  // same-wave LDS write->read is in-order; no barrier needed

  // ---- stage 3: recon = d1 @ Wd2 + bd2, K=64, 64 cols ----
  float4v accr[4][4];
#pragma unroll
  for (int m = 0; m < 4; ++m)
#pragma unroll
    for (int t = 0; t < 4; ++t) accr[m][t] = (float4v){0.f, 0.f, 0.f, 0.f};

#pragma unroll
  for (int kt3 = 0; kt3 < 2; ++kt3) {
    short8 df[4];
#pragma unroll
    for (int m = 0; m < 4; ++m)
      df[m] = *(const short8*)(wls + (((m * 16 + p) * 128 + kt3 * 64 + q * 16) ^ sw));
#pragma unroll
    for (int t3 = 0; t3 < 4; ++t3) {
      short8 wf = *(const short8*)(W6 + (long long)(t3 * 16 + p) * 64 + kt3 * 32 + q * 8);
#pragma unroll
      for (int m = 0; m < 4; ++m)
        accr[m][t3] = __builtin_amdgcn_mfma_f32_16x16x32_bf16(wf, df[m], accr[m][t3], 0, 0, 0);
    }
  }

#pragma unroll
  for (int m = 0; m < 4; ++m) {
    int row = rowbase + m * 16 + p;
    if (row < n) {
#pragma unroll
      for (int t3 = 0; t3 < 4; ++t3) {
        float4v bb = *(const float4v*)(bd2v + t3 * 16 + q * 4);
        float4v v;
#pragma unroll
        for (int r = 0; r < 4; ++r) v[r] = accr[m][t3][r] + bb[r];
        *(float4v*)(recon + (long long)row * 64 + t3 * 16 + q * 4) = v;
      }
    }
  }
}

// ======================= layer-2: fused-dec + cli GEMM in one launch =========
// dec blocks are the FIRST range (blk0=0, so dec_worker's blockIdx math is
// unchanged); gemm2b blocks follow. Both ready after pull2-L2.
__global__ __launch_bounds__(256, 2) void dec_l2_kernel(
    const bf16* __restrict__ m2ct, const bf16* __restrict__ htxn,
    const ushort* __restrict__ W3, const float* __restrict__ b2ct,
    const ushort* __restrict__ W5, const float* __restrict__ bd1v,
    const ushort* __restrict__ W6, const float* __restrict__ bd2v,
    float* __restrict__ zout, float* __restrict__ recon,
    const bf16* __restrict__ m2tc, const bf16* __restrict__ hcli,
    const ushort* __restrict__ W4, const float* __restrict__ b2tc,
    float* __restrict__ outb, long long zcli_base,
    int nT, int nC, int nblkA) {
  __shared__ __align__(16) char zls[65536];  // 4 waves x 16KB (dec branch)
  if ((int)blockIdx.x < nblkA)
    dec_worker(zls, m2ct, htxn, W3, b2ct, W5, bd1v, W6, bd2v, zout, recon, nT);
  else
    gemm_worker<8, 8, 4, AT_BF16, AT_BF16, true, 1>(
        m2tc, 128, hcli, 128, W4, b2tc, outb, zcli_base, 128, nC, 0, nblkA);
}

// ======================= host ================================================
extern "C" void kernel_launch(void* const* d_in, const int* in_sizes, int n_in,
                              void* d_out, int out_size, void* d_ws,
                              size_t ws_size, hipStream_t stream) {
  const float* x_txn = (const float*)d_in[0];
  const float* x_cli = (const float*)d_in[1];
  const int* ct_src = (const int*)d_in[2];
  const int* ct_dst = (const int*)d_in[3];
  const int* tc_src = (const int*)d_in[4];
  const int* tc_dst = (const int*)d_in[5];
  const float* W1ctl = (const float*)d_in[6];
  const float* b1ct  = (const float*)d_in[7];
  const float* W1ctr = (const float*)d_in[8];
  const float* W1tcl = (const float*)d_in[9];
  const float* b1tc  = (const float*)d_in[10];
  const float* W1tcr = (const float*)d_in[11];
  const float* W2ctl = (const float*)d_in[12];
  const float* b2ct  = (const float*)d_in[13];
  const float* W2ctr = (const float*)d_in[14];
  const float* W2tcl = (const float*)d_in[15];
  const float* b2tc  = (const float*)d_in[16];
  const float* W2tcr = (const float*)d_in[17];
  const float* Wd1   = (const float*)d_in[18];
  const float* bd1   = (const float*)d_in[19];
  const float* Wd2   = (const float*)d_in[20];
  const float* bd2   = (const float*)d_in[21];

  const int E = in_sizes[2];  // 600000
  const int NT = 100000, NC = 20000;
  const int NBK_CT = (NT + 255) >> 8;  // 391
  const int NBK_TC = (NC + 255) >> 8;  // 79

  // ---- workspace carve ----
  size_t o = 0;
  auto carve = [&](size_t bytes) {
    void* p = (char*)d_ws + o;
    o = (o + bytes + 255) & ~(size_t)255;
    return p;
  };
  int* bcnt_ct = (int*)carve((size_t)NBK_CT * 4);       // zeroed
  int* bcnt_tc = (int*)carve((size_t)NBK_TC * 4);       // zeroed (same page run)
  size_t zero_bytes = o;
  int* boff_ct = (int*)carve((size_t)(NBK_CT + 1) * 4);
  int* boff_tc = (int*)carve((size_t)(NBK_TC + 1) * 4);
  int* bcur_ct = (int*)carve((size_t)NBK_CT * 4);
  int* bcur_tc = (int*)carve((size_t)NBK_TC * 4);
  uint2* se_ct = (uint2*)carve((size_t)E * 8);
  uint2* se_tc = (uint2*)carve((size_t)E * 8);
  int* off_ct = (int*)carve((size_t)(NT + 1) * 4);
  int* off_tc = (int*)carve((size_t)(NC + 1) * 4);
  int* csr_ct = (int*)carve((size_t)E * 4);
  int* csr_tc = (int*)carve((size_t)E * 4);
  ushort* Wt1 = (ushort*)carve((size_t)96 * 128 * 2);
  ushort* Wt2 = (ushort*)carve((size_t)96 * 128 * 2);
  ushort* Wt3 = (ushort*)carve((size_t)256 * 128 * 2);
  ushort* Wt4 = (ushort*)carve((size_t)256 * 128 * 2);
  ushort* Wt5 = (ushort*)carve((size_t)128 * 64 * 2);
  ushort* Wt6 = (ushort*)carve((size_t)64 * 64 * 2);
  bf16* mean1_ct = (bf16*)carve((size_t)NT * 32 * 2);
  bf16* mean1_tc = (bf16*)carve((size_t)NC * 64 * 2);
  bf16* h_txn    = (bf16*)carve((size_t)NT * 128 * 2);
  bf16* h_cli    = (bf16*)carve((size_t)NC * 128 * 2);
  bf16* mean2_ct = (bf16*)carve((size_t)NT * 128 * 2);
  bf16* mean2_tc = (bf16*)carve((size_t)NC * 128 * 2);
  (void)ws_size;

  hipMemsetAsync(d_ws, 0, zero_bytes, stream);

  const int tb = 256;
  const int CH = (E + 4095) / 4096;  // 147 chunks per edge type

  // ---- fused weight transposes (1 launch) ----
  {
    TJobs js;
    auto blocks = [](int k, int ncol) { return (k * ncol + 255) / 256; };
    int boff = 0;
    auto setj = [&](int idx, const float* wl, const float* wr, ushort* dst,
                    int da, int k, int ncol) {
      js.j[idx] = TJob{wl, wr, dst, da, k, ncol, boff};
      boff += blocks(k, ncol);
    };
    setj(0, W1ctl, W1ctr, Wt1, 32, 96, 128);
    setj(1, W1tcl, W1tcr, Wt2, 64, 96, 128);
    setj(2, W2ctl, W2ctr, Wt3, 128, 256, 128);
    setj(3, W2tcl, W2tcr, Wt4, 128, 256, 128);
    setj(4, Wd1, Wd1, Wt5, 128, 128, 64);
    setj(5, Wd2, Wd2, Wt6, 64, 64, 64);
    transpose6_kernel<<<boff, tb, 0, stream>>>(js);
  }

  // ---- CSR build: two-level counting sort (both edge types fused) ----
  bhist_kernel<<<2 * CH, tb, 0, stream>>>(ct_dst, bcnt_ct, NBK_CT,
                                          tc_dst, bcnt_tc, NBK_TC, E, CH);
  bscan_kernel<<<2, 512, 0, stream>>>(bcnt_ct, boff_ct, bcur_ct, NBK_CT,
                                      bcnt_tc, boff_tc, bcur_tc, NBK_TC);
  multisplit_kernel<<<2 * CH, tb, 0, stream>>>(
      ct_src, ct_dst, bcur_ct, se_ct, NBK_CT,
      tc_src, tc_dst, bcur_tc, se_tc, NBK_TC, E, CH);
  csr_fine_kernel<<<NBK_CT + NBK_TC, tb, 0, stream>>>(
      se_ct, boff_ct, off_ct, csr_ct, NT, NBK_CT,
      se_tc, boff_tc, off_tc, csr_tc, NC);

  const int pbA = (NT + 3) / 4, pbB = (NC + 3) / 4;
  const int gA = (NT + 255) / 256;   // 391 (MT=4 / dec blocks)
  const int gB = (NC + 63) / 64;     // 313 (MT=1 blocks)

  // ---- layer 1: fused pull means, then both linears in one launch ----
  pull2_kernel<32, false, 64, false><<<pbA + pbB, tb, 0, stream>>>(
      off_ct, csr_ct, x_cli, mean1_ct, NT, NC,
      off_tc, csr_tc, x_txn, mean1_tc, NC, NT, pbA);

  gemm_l1_kernel<<<gA + gB, tb, 0, stream>>>(
      mean1_ct, x_txn, Wt1, b1ct, h_txn,
      mean1_tc, x_cli, Wt2, b1tc, h_cli, NT, NC, gA);

  // ---- layer 2: fused pull means ----
  pull2_kernel<128, true, 128, true><<<pbA + pbB, tb, 0, stream>>>(
      off_ct, csr_ct, h_cli, mean2_ct, NT, NC,
      off_tc, csr_tc, h_txn, mean2_tc, NC, NT, pbA);

  float* out = (float*)d_out;
  const long long ztxn_base = (long long)NT * 64;
  const long long zcli_base = ztxn_base + (long long)NT * 128;

  // ---- fused: (z_txn + decoder) blocks + z_cli GEMM blocks, one launch ----
  dec_l2_kernel<<<gA + gB, tb, 0, stream>>>(
      mean2_ct, h_txn, Wt3, b2ct, Wt5, bd1, Wt6, bd2,
      out + ztxn_base, out,
      mean2_tc, h_cli, Wt4, b2tc, out, zcli_base, NT, NC, gA);
}

// Round 7
// 338.420 us; speedup vs baseline: 1.1851x; 1.0846x over previous
//
#include <hip/hip_runtime.h>
#include <hip/hip_bf16.h>

typedef __hip_bfloat16 bf16;
typedef unsigned int uint;
typedef unsigned short ushort;
typedef __attribute__((ext_vector_type(8))) short short8;   // 8 bf16 = 4 VGPR
typedef __attribute__((ext_vector_type(4))) float float4v;  // MFMA acc

__device__ __forceinline__ float lo2f(uint v) { return __uint_as_float(v << 16); }
__device__ __forceinline__ float hi2f(uint v) { return __uint_as_float(v & 0xffff0000u); }
__device__ __forceinline__ ushort f2bu(float v) {
  union { bf16 h; ushort u; } x;
  x.h = __float2bfloat16(v);
  return x.u;
}
__device__ __forceinline__ uint packbf2(float a, float b) {
  return (uint)f2bu(a) | ((uint)f2bu(b) << 16);
}

#define BSH 8          // bucket shift: 256 nodes per bucket
#define NBK_MAX 391    // max buckets (txn side)

// ======================= fused weight transpose (6 jobs, 1 launch) ===========
struct TJob { const float* wl; const float* wr; ushort* dst; int da, k, ncol, boff; };
struct TJobs { TJob j[6]; };

__global__ void transpose6_kernel(TJobs js) {
  int b = blockIdx.x;
  int jj = 0;
#pragma unroll
  for (int t = 1; t < 6; ++t)
    if (b >= js.j[t].boff) jj = t;
  const TJob J = js.j[jj];
  int i = (b - J.boff) * 256 + threadIdx.x;
  if (i >= J.k * J.ncol) return;
  int k = i / J.ncol, c = i - k * J.ncol;
  const float* srcp = (k < J.da) ? (J.wl + (long long)k * J.ncol)
                                 : (J.wr + (long long)(k - J.da) * J.ncol);
  J.dst[(long long)c * J.k + k] = f2bu(srcp[c]);
}

// ======================= CSR build, two-level counting sort ==================
__global__ void bhist_kernel(const int* __restrict__ dA, int* __restrict__ cA, int nbkA,
                             const int* __restrict__ dB, int* __restrict__ cB, int nbkB,
                             int E, int chA) {
  __shared__ int h[NBK_MAX];
  int b = blockIdx.x;
  const int* dst; int* gc; int nbk;
  if (b < chA) { dst = dA; gc = cA; nbk = nbkA; }
  else         { b -= chA; dst = dB; gc = cB; nbk = nbkB; }
  for (int i = threadIdx.x; i < nbk; i += 256) h[i] = 0;
  __syncthreads();
  int e0 = b * 4096;
  for (int j = 0; j < 16; ++j) {
    int e = e0 + j * 256 + threadIdx.x;
    if (e < E) {
      uint B = (uint)dst[e] >> BSH;
      if (B < (uint)nbk) atomicAdd(&h[B], 1);
    }
  }
  __syncthreads();
  for (int i = threadIdx.x; i < nbk; i += 256)
    if (h[i]) atomicAdd(&gc[i], h[i]);
}

__global__ void bscan_kernel(const int* __restrict__ cA, int* __restrict__ oA,
                             int* __restrict__ uA, int nbkA,
                             const int* __restrict__ cB, int* __restrict__ oB,
                             int* __restrict__ uB, int nbkB) {
  __shared__ int s[512];
  const int* cnt; int* off; int* cur; int nbk;
  if (blockIdx.x == 0) { cnt = cA; off = oA; cur = uA; nbk = nbkA; }
  else                 { cnt = cB; off = oB; cur = uB; nbk = nbkB; }
  int t = threadIdx.x;
  int v = (t < nbk) ? cnt[t] : 0;
  s[t] = v;
  __syncthreads();
  for (int o = 1; o < 512; o <<= 1) {
    int x = (t >= o) ? s[t - o] : 0;
    __syncthreads();
    s[t] += x;
    __syncthreads();
  }
  if (t < nbk) { int ex = s[t] - v; off[t] = ex; cur[t] = ex; }
  if (t == nbk - 1) off[nbk] = s[t];
}

__global__ void multisplit_kernel(const int* __restrict__ sA, const int* __restrict__ dA,
                                  int* __restrict__ uA, uint2* __restrict__ seA, int nbkA,
                                  const int* __restrict__ sB, const int* __restrict__ dB,
                                  int* __restrict__ uB, uint2* __restrict__ seB, int nbkB,
                                  int E, int chA) {
  __shared__ int cnt[NBK_MAX];
  __shared__ int base[NBK_MAX];
  int b = blockIdx.x;
  const int *src, *dst; int* gcur; uint2* se; int nbk;
  if (b < chA) { src = sA; dst = dA; gcur = uA; se = seA; nbk = nbkA; }
  else         { b -= chA; src = sB; dst = dB; gcur = uB; se = seB; nbk = nbkB; }
  for (int i = threadIdx.x; i < nbk; i += 256) cnt[i] = 0;
  __syncthreads();
  int e0 = b * 4096;
  int mys[16], myd[16], myb[16], myr[16];
#pragma unroll
  for (int j = 0; j < 16; ++j) {
    int e = e0 + j * 256 + threadIdx.x;
    int s = 0, d = 0, bb = -1, r = 0;
    if (e < E) {
      s = src[e]; d = dst[e];
      uint B = (uint)d >> BSH;
      if (B < (uint)nbk) { bb = (int)B; r = atomicAdd(&cnt[bb], 1); }
    }
    mys[j] = s; myd[j] = d; myb[j] = bb; myr[j] = r;
  }
  __syncthreads();
  for (int i = threadIdx.x; i < nbk; i += 256) {
    int c = cnt[i];
    base[i] = c ? atomicAdd(&gcur[i], c) : 0;
  }
  __syncthreads();
#pragma unroll
  for (int j = 0; j < 16; ++j) {
    if (myb[j] >= 0) {
      uint2 v; v.x = (uint)mys[j]; v.y = (uint)myd[j];
      se[base[myb[j]] + myr[j]] = v;
    }
  }
}

__global__ void csr_fine_kernel(const uint2* __restrict__ seA, const int* __restrict__ boA,
                                int* __restrict__ offA, int* __restrict__ csrA, int nA, int nbkA,
                                const uint2* __restrict__ seB, const int* __restrict__ boB,
                                int* __restrict__ offB, int* __restrict__ csrB, int nB) {
  __shared__ int s[256];
  __shared__ int cur[256];
  int b = blockIdx.x;
  const uint2* se; const int* bo; int* off; int* csr; int n;
  if (b < nbkA) { se = seA; bo = boA; off = offA; csr = csrA; n = nA; }
  else          { b -= nbkA; se = seB; bo = boB; off = offB; csr = csrB; n = nB; }
  int t = threadIdx.x;
  int ebeg = bo[b], eend = bo[b + 1];
  cur[t] = 0;
  __syncthreads();
  for (int i = ebeg + t; i < eend; i += 256)
    atomicAdd(&cur[se[i].y & 255], 1);
  __syncthreads();
  int v = cur[t];
  s[t] = v;
  __syncthreads();
  for (int o = 1; o < 256; o <<= 1) {
    int x = (t >= o) ? s[t - o] : 0;
    __syncthreads();
    s[t] += x;
    __syncthreads();
  }
  int excl = s[t] - v;
  int node = b * 256 + t;
  if (node < n) off[node] = ebeg + excl;
  if (node == n - 1) off[n] = ebeg + excl + v;
  cur[t] = excl;
  __syncthreads();
  for (int i = ebeg + t; i < eend; i += 256) {
    uint2 e = se[i];
    int pos = ebeg + atomicAdd(&cur[e.y & 255], 1);
    csr[pos] = (int)e.x;
  }
}

// ======================= pull aggregation (mean, bf16 out) — R3-validated ====
__device__ __forceinline__ void acc8(float* a, uint4 v) {
  a[0] += lo2f(v.x); a[1] += hi2f(v.x);
  a[2] += lo2f(v.y); a[3] += hi2f(v.y);
  a[4] += lo2f(v.z); a[5] += hi2f(v.z);
  a[6] += lo2f(v.w); a[7] += hi2f(v.w);
}
__device__ __forceinline__ void acc4(float* a, float4 v) {
  a[0] += v.x; a[1] += v.y; a[2] += v.z; a[3] += v.w;
}

template <int D, bool XBF>
__device__ __forceinline__ void pull_worker(
    const int* __restrict__ off, const int* __restrict__ csr,
    const void* __restrict__ x, bf16* __restrict__ mean, int n, int nsrc,
    int blk0) {
  constexpr int EPL = XBF ? 8 : 4;    // elems per lane (16B either way)
  constexpr int LPR = D / EPL;        // lanes per row
  constexpr int PAR = 64 / LPR;       // edges in parallel
  int node = ((int)blockIdx.x - blk0) * 4 + (threadIdx.x >> 6);
  if (node >= n) return;  // wave-uniform
  int lane = threadIdx.x & 63;
  int h = lane / LPR, col = lane % LPR;
  int beg = off[node], deg = off[node + 1] - beg;
  float inv = 1.0f / fmaxf((float)deg, 1.0f);
  float a[EPL];
#pragma unroll
  for (int e = 0; e < EPL; ++e) a[e] = 0.f;

  int i = h;
  for (; i + 3 * PAR < deg; i += 4 * PAR) {
    int s0 = csr[beg + i];
    int s1 = csr[beg + i + PAR];
    int s2 = csr[beg + i + 2 * PAR];
    int s3 = csr[beg + i + 3 * PAR];
    s0 = ((unsigned)s0 < (unsigned)nsrc) ? s0 : 0;
    s1 = ((unsigned)s1 < (unsigned)nsrc) ? s1 : 0;
    s2 = ((unsigned)s2 < (unsigned)nsrc) ? s2 : 0;
    s3 = ((unsigned)s3 < (unsigned)nsrc) ? s3 : 0;
    if (XBF) {
      uint4 v0 = ((const uint4*)x)[(long long)s0 * LPR + col];
      uint4 v1 = ((const uint4*)x)[(long long)s1 * LPR + col];
      uint4 v2 = ((const uint4*)x)[(long long)s2 * LPR + col];
      uint4 v3 = ((const uint4*)x)[(long long)s3 * LPR + col];
      acc8(a, v0); acc8(a, v1); acc8(a, v2); acc8(a, v3);
    } else {
      float4 v0 = ((const float4*)x)[(long long)s0 * LPR + col];
      float4 v1 = ((const float4*)x)[(long long)s1 * LPR + col];
      float4 v2 = ((const float4*)x)[(long long)s2 * LPR + col];
      float4 v3 = ((const float4*)x)[(long long)s3 * LPR + col];
      acc4(a, v0); acc4(a, v1); acc4(a, v2); acc4(a, v3);
    }
  }
  for (; i < deg; i += PAR) {
    int s = csr[beg + i];
    s = ((unsigned)s < (unsigned)nsrc) ? s : 0;
    if (XBF) {
      uint4 v = ((const uint4*)x)[(long long)s * LPR + col];
      acc8(a, v);
    } else {
      float4 v = ((const float4*)x)[(long long)s * LPR + col];
      acc4(a, v);
    }
  }

#pragma unroll
  for (int m = LPR; m < 64; m <<= 1) {
#pragma unroll
    for (int e = 0; e < EPL; ++e) a[e] += __shfl_xor(a[e], m);
  }
  if (h == 0) {
    if (XBF) {
      uint4 o4;
      o4.x = packbf2(a[0] * inv, a[1] * inv);
      o4.y = packbf2(a[2] * inv, a[3] * inv);
      o4.z = packbf2(a[4] * inv, a[5] * inv);
      o4.w = packbf2(a[6] * inv, a[7] * inv);
      ((uint4*)mean)[(long long)node * LPR + col] = o4;
    } else {
      uint2 o2;
      o2.x = packbf2(a[0] * inv, a[1] * inv);
      o2.y = packbf2(a[2] * inv, a[3] * inv);
      ((uint2*)mean)[(long long)node * LPR + col] = o2;
    }
  }
}

template <int DA, bool XA, int DB, bool XB>
__global__ __launch_bounds__(256) void pull2_kernel(
    const int* __restrict__ offA, const int* __restrict__ csrA,
    const void* __restrict__ xA, bf16* __restrict__ meanA, int nA, int nsrcA,
    const int* __restrict__ offB, const int* __restrict__ csrB,
    const void* __restrict__ xB, bf16* __restrict__ meanB, int nB, int nsrcB,
    int nblkA) {
  if ((int)blockIdx.x < nblkA)
    pull_worker<DA, XA>(offA, csrA, xA, meanA, nA, nsrcA, 0);
  else
    pull_worker<DB, XB>(offB, csrB, xB, meanB, nB, nsrcB, nblkA);
}

// ======================= MFMA GEMM worker (no LDS, MT row-tiles) =============
#define AT_BF16 0
#define AT_F32  1
template <int KT, int NCT, int K0T, int A0T, int A1T, bool OUTF32, int MT>
__device__ __forceinline__ void gemm_worker(
    const void* __restrict__ A0, int lda0,
    const void* __restrict__ A1, int lda1,
    const ushort* __restrict__ Wt, const float* __restrict__ bias,
    void* __restrict__ C, long long cbase, int ldc, int n, int relu, int blk0) {
  constexpr int K = KT * 32;
  int tid = threadIdx.x;
  int wave = tid >> 6, lane = tid & 63;
  int p = lane & 15, q = lane >> 4;
  int rowbase = ((int)blockIdx.x - blk0) * (64 * MT) + wave * (16 * MT);

  int rcl[MT];
#pragma unroll
  for (int m = 0; m < MT; ++m) rcl[m] = min(rowbase + m * 16 + p, n - 1);

  float4v acc[MT][NCT];
#pragma unroll
  for (int m = 0; m < MT; ++m)
#pragma unroll
    for (int t = 0; t < NCT; ++t) acc[m][t] = (float4v){0.f, 0.f, 0.f, 0.f};

#pragma unroll
  for (int kt = 0; kt < KT; ++kt) {
    const bool seg0 = (kt < K0T);
    const void* ab = seg0 ? A0 : A1;
    const int lda = seg0 ? lda0 : lda1;
    const int kof = (seg0 ? kt : (kt - K0T)) * 32;
    const int at = seg0 ? A0T : A1T;
    short8 af[MT];
#pragma unroll
    for (int m = 0; m < MT; ++m) {
      long long base = (long long)rcl[m] * lda + kof + q * 8;
      if (at == AT_BF16) {
        af[m] = *(const short8*)((const bf16*)ab + base);
      } else {
        const float* fb = (const float*)ab + base;
        float4 a = *(const float4*)fb;
        float4 b = *(const float4*)(fb + 4);
        short8 r;
        r[0] = (short)f2bu(a.x); r[1] = (short)f2bu(a.y);
        r[2] = (short)f2bu(a.z); r[3] = (short)f2bu(a.w);
        r[4] = (short)f2bu(b.x); r[5] = (short)f2bu(b.y);
        r[6] = (short)f2bu(b.z); r[7] = (short)f2bu(b.w);
        af[m] = r;
      }
    }
#pragma unroll
    for (int t = 0; t < NCT; ++t) {
      int c = t * 16 + p;
      short8 bfr = *(const short8*)(Wt + (long long)c * K + kt * 32 + q * 8);
#pragma unroll
      for (int m = 0; m < MT; ++m)
        acc[m][t] = __builtin_amdgcn_mfma_f32_16x16x32_bf16(af[m], bfr, acc[m][t], 0, 0, 0);
    }
  }

#pragma unroll
  for (int m = 0; m < MT; ++m) {
#pragma unroll
    for (int t = 0; t < NCT; ++t) {
      int c = t * 16 + p;
      float bv = bias[c];
#pragma unroll
      for (int r = 0; r < 4; ++r) {
        int row = rowbase + m * 16 + q * 4 + r;
        if (row < n) {
          float v = acc[m][t][r] + bv;
          if (relu) v = fmaxf(v, 0.f);
          long long idx = cbase + (long long)row * ldc + c;
          if (OUTF32) ((float*)C)[idx] = v;
          else        ((bf16*)C)[idx] = __float2bfloat16(v);
        }
      }
    }
  }
}

// ======================= layer-1: both GEMMs in one launch ===================
// R5-validated pair fusion; R6: cli branch MT 1->4 (coverage comes from the
// partner range, so per-wave B-load amortization wins).
__global__ __launch_bounds__(256, 2) void gemm_l1_kernel(
    const bf16* __restrict__ m1ct, const float* __restrict__ xtxn,
    const ushort* __restrict__ Wt1, const float* __restrict__ b1ct,
    bf16* __restrict__ htxn,
    const bf16* __restrict__ m1tc, const float* __restrict__ xcli,
    const ushort* __restrict__ Wt2, const float* __restrict__ b1tc,
    bf16* __restrict__ hcli, int nT, int nC, int nblkA) {
  if ((int)blockIdx.x < nblkA)
    gemm_worker<3, 8, 1, AT_BF16, AT_F32, false, 4>(
        m1ct, 32, xtxn, 64, Wt1, b1ct, htxn, 0, 128, nT, 1, 0);
  else
    gemm_worker<3, 8, 2, AT_BF16, AT_F32, false, 4>(
        m1tc, 64, xcli, 32, Wt2, b1tc, hcli, 0, 128, nC, 1, nblkA);
}

// ======================= fused L2-txn GEMM + decoder worker ==================
// R6: stage-1 B operand (Wt3, 64KB) is staged into the block's LDS once and
// shared by all 4 waves (it was idle during stage-1; z only needs it after).
// Replaces 64 L2 global loads/wave with ds_read_b128 (~120 vs ~300cyc) and
// cuts 256KB/block of L2 traffic. XOR swizzle ((c&7)<<4) => 2 lanes/bank on
// both write and read (free tier). One extra barrier before the z epilogue
// overwrites the region. Numerics bit-identical.
__device__ __forceinline__ void dec_worker(
    char* zls,
    const bf16* __restrict__ A0,   // mean2_ct [n][128]
    const bf16* __restrict__ A1,   // h_txn    [n][128]
    const ushort* __restrict__ W3, // Wt3 [128][256]
    const float* __restrict__ b2,  // [128]
    const ushort* __restrict__ W5, // Wt5 [64][128]
    const float* __restrict__ bd1v,// [64]
    const ushort* __restrict__ W6, // Wt6 [64][64]
    const float* __restrict__ bd2v,// [64]
    float* __restrict__ zout,      // d_out + ztxn_base, ld 128
    float* __restrict__ recon,     // d_out, ld 64
    int n) {
  int tid = threadIdx.x;
  int wave = tid >> 6, lane = tid & 63;
  int p = lane & 15, q = lane >> 4;
  int rowbase = blockIdx.x * 256 + wave * 64;
  char* wls = zls + wave * 16384;
  const int sw = (p & 7) << 4;  // XOR swizzle

  // ---- stage Wt3 (64KB) into LDS, swizzled; all 4 waves cooperate ----
#pragma unroll
  for (int it = 0; it < 16; ++it) {
    int idx = it * 256 + tid;          // 16B granule, 4096 total
    int byte = idx << 4;
    int c = byte >> 9;                 // 512 B per weight column
    uint4 v = ((const uint4*)W3)[idx];
    *(uint4*)(zls + (byte ^ ((c & 7) << 4))) = v;
  }
  __syncthreads();

  int rcl[4];
#pragma unroll
  for (int m = 0; m < 4; ++m) rcl[m] = min(rowbase + m * 16 + p, n - 1);

  // ---- stage 1: z accumulators (transposed layout via swapped operands) ----
  float4v accz[4][8];
#pragma unroll
  for (int m = 0; m < 4; ++m)
#pragma unroll
    for (int t = 0; t < 8; ++t) accz[m][t] = (float4v){0.f, 0.f, 0.f, 0.f};

#pragma unroll
  for (int kt = 0; kt < 8; ++kt) {
    const bf16* ab = (kt < 4) ? A0 : A1;
    const int kof = (kt & 3) * 32;
    short8 af[4];
#pragma unroll
    for (int m = 0; m < 4; ++m)
      af[m] = *(const short8*)(ab + (long long)rcl[m] * 128 + kof + q * 8);
#pragma unroll
    for (int t = 0; t < 8; ++t) {
      int c = t * 16 + p;
      short8 bfr = *(const short8*)(zls + ((c * 512 + kt * 64 + q * 16) ^ ((c & 7) << 4)));
#pragma unroll
      for (int m = 0; m < 4; ++m)
        accz[m][t] = __builtin_amdgcn_mfma_f32_16x16x32_bf16(bfr, af[m], accz[m][t], 0, 0, 0);
    }
  }
  __syncthreads();  // all W3 reads done before z overwrites the LDS

  // epilogue: z -> global f32 (+bias), z -> LDS bf16 (row-major [64][256B], swz)
#pragma unroll
  for (int m = 0; m < 4; ++m) {
    int lr = m * 16 + p;
    int row = rowbase + lr;
#pragma unroll
    for (int t = 0; t < 8; ++t) {
      float4v bz = *(const float4v*)(b2 + t * 16 + q * 4);
      float4v v;
#pragma unroll
      for (int r = 0; r < 4; ++r) v[r] = accz[m][t][r] + bz[r];
      if (row < n)
        *(float4v*)(zout + (long long)row * 128 + t * 16 + q * 4) = v;
      uint2 u;
      u.x = packbf2(v[0], v[1]);
      u.y = packbf2(v[2], v[3]);
      *(uint2*)(wls + (((lr * 256 + t * 32 + q * 8)) ^ sw)) = u;
    }
  }
  __syncthreads();

  // ---- stage 2: d1 = relu(z @ Wd1 + bd1), K=128, 64 cols ----
  float4v accd[4][4];
#pragma unroll
  for (int m = 0; m < 4; ++m)
#pragma unroll
    for (int t = 0; t < 4; ++t) accd[m][t] = (float4v){0.f, 0.f, 0.f, 0.f};

#pragma unroll
  for (int kt2 = 0; kt2 < 4; ++kt2) {
    short8 zf[4];
#pragma unroll
    for (int m = 0; m < 4; ++m)
      zf[m] = *(const short8*)(wls + (((m * 16 + p) * 256 + kt2 * 64 + q * 16) ^ sw));
#pragma unroll
    for (int t2 = 0; t2 < 4; ++t2) {
      short8 wf = *(const short8*)(W5 + (long long)(t2 * 16 + p) * 128 + kt2 * 32 + q * 8);
#pragma unroll
      for (int m = 0; m < 4; ++m)
        accd[m][t2] = __builtin_amdgcn_mfma_f32_16x16x32_bf16(wf, zf[m], accd[m][t2], 0, 0, 0);
    }
  }
  __syncthreads();  // all z-reads done before overwriting region with d1

  // d1 (relu, bf16) -> LDS row-major [64][128B], same swizzle
#pragma unroll
  for (int m = 0; m < 4; ++m) {
    int lr = m * 16 + p;
#pragma unroll
    for (int t2 = 0; t2 < 4; ++t2) {
      float4v bb = *(const float4v*)(bd1v + t2 * 16 + q * 4);
      float4v v;
#pragma unroll
      for (int r = 0; r < 4; ++r) v[r] = fmaxf(accd[m][t2][r] + bb[r], 0.f);
      uint2 u;
      u.x = packbf2(v[0], v[1]);
      u.y = packbf2(v[2], v[3]);
      *(uint2*)(wls + (((lr * 128 + t2 * 32 + q * 8)) ^ sw)) = u;
    }
  }
  // same-wave LDS write->read is in-order; no barrier needed

  // ---- stage 3: recon = d1 @ Wd2 + bd2, K=64, 64 cols ----
  float4v accr[4][4];
#pragma unroll
  for (int m = 0; m < 4; ++m)
#pragma unroll
    for (int t = 0; t < 4; ++t) accr[m][t] = (float4v){0.f, 0.f, 0.f, 0.f};

#pragma unroll
  for (int kt3 = 0; kt3 < 2; ++kt3) {
    short8 df[4];
#pragma unroll
    for (int m = 0; m < 4; ++m)
      df[m] = *(const short8*)(wls + (((m * 16 + p) * 128 + kt3 * 64 + q * 16) ^ sw));
#pragma unroll
    for (int t3 = 0; t3 < 4; ++t3) {
      short8 wf = *(const short8*)(W6 + (long long)(t3 * 16 + p) * 64 + kt3 * 32 + q * 8);
#pragma unroll
      for (int m = 0; m < 4; ++m)
        accr[m][t3] = __builtin_amdgcn_mfma_f32_16x16x32_bf16(wf, df[m], accr[m][t3], 0, 0, 0);
    }
  }

#pragma unroll
  for (int m = 0; m < 4; ++m) {
    int row = rowbase + m * 16 + p;
    if (row < n) {
#pragma unroll
      for (int t3 = 0; t3 < 4; ++t3) {
        float4v bb = *(const float4v*)(bd2v + t3 * 16 + q * 4);
        float4v v;
#pragma unroll
        for (int r = 0; r < 4; ++r) v[r] = accr[m][t3][r] + bb[r];
        *(float4v*)(recon + (long long)row * 64 + t3 * 16 + q * 4) = v;
      }
    }
  }
}

// ======================= layer-2: fused-dec + cli GEMM in one launch =========
__global__ __launch_bounds__(256, 2) void dec_l2_kernel(
    const bf16* __restrict__ m2ct, const bf16* __restrict__ htxn,
    const ushort* __restrict__ W3, const float* __restrict__ b2ct,
    const ushort* __restrict__ W5, const float* __restrict__ bd1v,
    const ushort* __restrict__ W6, const float* __restrict__ bd2v,
    float* __restrict__ zout, float* __restrict__ recon,
    const bf16* __restrict__ m2tc, const bf16* __restrict__ hcli,
    const ushort* __restrict__ W4, const float* __restrict__ b2tc,
    float* __restrict__ outb, long long zcli_base,
    int nT, int nC, int nblkA) {
  __shared__ __align__(16) char zls[65536];  // dec branch: W3 stage, then z/d1
  if ((int)blockIdx.x < nblkA)
    dec_worker(zls, m2ct, htxn, W3, b2ct, W5, bd1v, W6, bd2v, zout, recon, nT);
  else
    gemm_worker<8, 8, 4, AT_BF16, AT_BF16, true, 4>(
        m2tc, 128, hcli, 128, W4, b2tc, outb, zcli_base, 128, nC, 0, nblkA);
}

// ======================= host ================================================
extern "C" void kernel_launch(void* const* d_in, const int* in_sizes, int n_in,
                              void* d_out, int out_size, void* d_ws,
                              size_t ws_size, hipStream_t stream) {
  const float* x_txn = (const float*)d_in[0];
  const float* x_cli = (const float*)d_in[1];
  const int* ct_src = (const int*)d_in[2];
  const int* ct_dst = (const int*)d_in[3];
  const int* tc_src = (const int*)d_in[4];
  const int* tc_dst = (const int*)d_in[5];
  const float* W1ctl = (const float*)d_in[6];
  const float* b1ct  = (const float*)d_in[7];
  const float* W1ctr = (const float*)d_in[8];
  const float* W1tcl = (const float*)d_in[9];
  const float* b1tc  = (const float*)d_in[10];
  const float* W1tcr = (const float*)d_in[11];
  const float* W2ctl = (const float*)d_in[12];
  const float* b2ct  = (const float*)d_in[13];
  const float* W2ctr = (const float*)d_in[14];
  const float* W2tcl = (const float*)d_in[15];
  const float* b2tc  = (const float*)d_in[16];
  const float* W2tcr = (const float*)d_in[17];
  const float* Wd1   = (const float*)d_in[18];
  const float* bd1   = (const float*)d_in[19];
  const float* Wd2   = (const float*)d_in[20];
  const float* bd2   = (const float*)d_in[21];

  const int E = in_sizes[2];  // 600000
  const int NT = 100000, NC = 20000;
  const int NBK_CT = (NT + 255) >> 8;  // 391
  const int NBK_TC = (NC + 255) >> 8;  // 79

  // ---- workspace carve ----
  size_t o = 0;
  auto carve = [&](size_t bytes) {
    void* p = (char*)d_ws + o;
    o = (o + bytes + 255) & ~(size_t)255;
    return p;
  };
  int* bcnt_ct = (int*)carve((size_t)NBK_CT * 4);       // zeroed
  int* bcnt_tc = (int*)carve((size_t)NBK_TC * 4);       // zeroed (same page run)
  size_t zero_bytes = o;
  int* boff_ct = (int*)carve((size_t)(NBK_CT + 1) * 4);
  int* boff_tc = (int*)carve((size_t)(NBK_TC + 1) * 4);
  int* bcur_ct = (int*)carve((size_t)NBK_CT * 4);
  int* bcur_tc = (int*)carve((size_t)NBK_TC * 4);
  uint2* se_ct = (uint2*)carve((size_t)E * 8);
  uint2* se_tc = (uint2*)carve((size_t)E * 8);
  int* off_ct = (int*)carve((size_t)(NT + 1) * 4);
  int* off_tc = (int*)carve((size_t)(NC + 1) * 4);
  int* csr_ct = (int*)carve((size_t)E * 4);
  int* csr_tc = (int*)carve((size_t)E * 4);
  ushort* Wt1 = (ushort*)carve((size_t)96 * 128 * 2);
  ushort* Wt2 = (ushort*)carve((size_t)96 * 128 * 2);
  ushort* Wt3 = (ushort*)carve((size_t)256 * 128 * 2);
  ushort* Wt4 = (ushort*)carve((size_t)256 * 128 * 2);
  ushort* Wt5 = (ushort*)carve((size_t)128 * 64 * 2);
  ushort* Wt6 = (ushort*)carve((size_t)64 * 64 * 2);
  bf16* mean1_ct = (bf16*)carve((size_t)NT * 32 * 2);
  bf16* mean1_tc = (bf16*)carve((size_t)NC * 64 * 2);
  bf16* h_txn    = (bf16*)carve((size_t)NT * 128 * 2);
  bf16* h_cli    = (bf16*)carve((size_t)NC * 128 * 2);
  bf16* mean2_ct = (bf16*)carve((size_t)NT * 128 * 2);
  bf16* mean2_tc = (bf16*)carve((size_t)NC * 128 * 2);
  (void)ws_size;

  hipMemsetAsync(d_ws, 0, zero_bytes, stream);

  const int tb = 256;
  const int CH = (E + 4095) / 4096;  // 147 chunks per edge type

  // ---- fused weight transposes (1 launch) ----
  {
    TJobs js;
    auto blocks = [](int k, int ncol) { return (k * ncol + 255) / 256; };
    int boff = 0;
    auto setj = [&](int idx, const float* wl, const float* wr, ushort* dst,
                    int da, int k, int ncol) {
      js.j[idx] = TJob{wl, wr, dst, da, k, ncol, boff};
      boff += blocks(k, ncol);
    };
    setj(0, W1ctl, W1ctr, Wt1, 32, 96, 128);
    setj(1, W1tcl, W1tcr, Wt2, 64, 96, 128);
    setj(2, W2ctl, W2ctr, Wt3, 128, 256, 128);
    setj(3, W2tcl, W2tcr, Wt4, 128, 256, 128);
    setj(4, Wd1, Wd1, Wt5, 128, 128, 64);
    setj(5, Wd2, Wd2, Wt6, 64, 64, 64);
    transpose6_kernel<<<boff, tb, 0, stream>>>(js);
  }

  // ---- CSR build: two-level counting sort (both edge types fused) ----
  bhist_kernel<<<2 * CH, tb, 0, stream>>>(ct_dst, bcnt_ct, NBK_CT,
                                          tc_dst, bcnt_tc, NBK_TC, E, CH);
  bscan_kernel<<<2, 512, 0, stream>>>(bcnt_ct, boff_ct, bcur_ct, NBK_CT,
                                      bcnt_tc, boff_tc, bcur_tc, NBK_TC);
  multisplit_kernel<<<2 * CH, tb, 0, stream>>>(
      ct_src, ct_dst, bcur_ct, se_ct, NBK_CT,
      tc_src, tc_dst, bcur_tc, se_tc, NBK_TC, E, CH);
  csr_fine_kernel<<<NBK_CT + NBK_TC, tb, 0, stream>>>(
      se_ct, boff_ct, off_ct, csr_ct, NT, NBK_CT,
      se_tc, boff_tc, off_tc, csr_tc, NC);

  const int pbA = (NT + 3) / 4, pbB = (NC + 3) / 4;
  const int gA = (NT + 255) / 256;   // 391 (MT=4 / dec blocks)
  const int gB = (NC + 255) / 256;   // 79  (cli MT=4 blocks)

  // ---- layer 1: fused pull means, then both linears in one launch ----
  pull2_kernel<32, false, 64, false><<<pbA + pbB, tb, 0, stream>>>(
      off_ct, csr_ct, x_cli, mean1_ct, NT, NC,
      off_tc, csr_tc, x_txn, mean1_tc, NC, NT, pbA);

  gemm_l1_kernel<<<gA + gB, tb, 0, stream>>>(
      mean1_ct, x_txn, Wt1, b1ct, h_txn,
      mean1_tc, x_cli, Wt2, b1tc, h_cli, NT, NC, gA);

  // ---- layer 2: fused pull means ----
  pull2_kernel<128, true, 128, true><<<pbA + pbB, tb, 0, stream>>>(
      off_ct, csr_ct, h_cli, mean2_ct, NT, NC,
      off_tc, csr_tc, h_txn, mean2_tc, NC, NT, pbA);

  float* out = (float*)d_out;
  const long long ztxn_base = (long long)NT * 64;
  const long long zcli_base = ztxn_base + (long long)NT * 128;

  // ---- fused: (z_txn + decoder) blocks + z_cli GEMM blocks, one launch ----
  dec_l2_kernel<<<gA + gB, tb, 0, stream>>>(
      mean2_ct, h_txn, Wt3, b2ct, Wt5, bd1, Wt6, bd2,
      out + ztxn_base, out,
      mean2_tc, h_cli, Wt4, b2tc, out, zcli_base, NT, NC, gA);
}

// Round 8
// 334.737 us; speedup vs baseline: 1.1981x; 1.0110x over previous
//
#include <hip/hip_runtime.h>
#include <hip/hip_bf16.h>

typedef __hip_bfloat16 bf16;
typedef unsigned int uint;
typedef unsigned short ushort;
typedef __attribute__((ext_vector_type(8))) short short8;   // 8 bf16 = 4 VGPR
typedef __attribute__((ext_vector_type(4))) float float4v;  // MFMA acc
typedef __attribute__((ext_vector_type(2))) float float2v;  // v_pk_add_f32 pair

__device__ __forceinline__ float lo2f(uint v) { return __uint_as_float(v << 16); }
__device__ __forceinline__ float hi2f(uint v) { return __uint_as_float(v & 0xffff0000u); }
__device__ __forceinline__ ushort f2bu(float v) {
  union { bf16 h; ushort u; } x;
  x.h = __float2bfloat16(v);
  return x.u;
}
__device__ __forceinline__ uint packbf2(float a, float b) {
  return (uint)f2bu(a) | ((uint)f2bu(b) << 16);
}

#define BSH 8          // bucket shift: 256 nodes per bucket
#define NBK_MAX 391    // max buckets (txn side)

// ======================= weight transpose jobs ===============================
struct TJob { const float* wl; const float* wr; ushort* dst; int da, k, ncol, boff; };
struct TJobs { TJob j[6]; };

// ======================= fused transpose + bhist (1 launch) ==================
// Both depend only on kernel inputs; block-range split removes one launch gap.
__global__ __launch_bounds__(256) void tr_bhist_kernel(
    TJobs js,
    const int* __restrict__ dA, int* __restrict__ cA, int nbkA,
    const int* __restrict__ dB, int* __restrict__ cB, int nbkB,
    int E, int chA) {
  __shared__ int h[NBK_MAX];
  int b = blockIdx.x;
  int nbh = 2 * chA;
  if (b < nbh) {
    // ---- bhist: coarse histogram of dst>>BSH ----
    const int* dst; int* gc; int nbk;
    if (b < chA) { dst = dA; gc = cA; nbk = nbkA; }
    else         { b -= chA; dst = dB; gc = cB; nbk = nbkB; }
    for (int i = threadIdx.x; i < nbk; i += 256) h[i] = 0;
    __syncthreads();
    int e0 = b * 4096;
    for (int j = 0; j < 16; ++j) {
      int e = e0 + j * 256 + threadIdx.x;
      if (e < E) {
        uint B = (uint)dst[e] >> BSH;
        if (B < (uint)nbk) atomicAdd(&h[B], 1);
      }
    }
    __syncthreads();
    for (int i = threadIdx.x; i < nbk; i += 256)
      if (h[i]) atomicAdd(&gc[i], h[i]);
  } else {
    // ---- transpose6 ----
    b -= nbh;
    int jj = 0;
#pragma unroll
    for (int t = 1; t < 6; ++t)
      if (b >= js.j[t].boff) jj = t;
    const TJob J = js.j[jj];
    int i = (b - J.boff) * 256 + threadIdx.x;
    if (i >= J.k * J.ncol) return;
    int k = i / J.ncol, c = i - k * J.ncol;
    const float* srcp = (k < J.da) ? (J.wl + (long long)k * J.ncol)
                                   : (J.wr + (long long)(k - J.da) * J.ncol);
    J.dst[(long long)c * J.k + k] = f2bu(srcp[c]);
  }
}

// ======================= CSR build (rest of the chain) =======================
__global__ void bscan_kernel(const int* __restrict__ cA, int* __restrict__ oA,
                             int* __restrict__ uA, int nbkA,
                             const int* __restrict__ cB, int* __restrict__ oB,
                             int* __restrict__ uB, int nbkB) {
  __shared__ int s[512];
  const int* cnt; int* off; int* cur; int nbk;
  if (blockIdx.x == 0) { cnt = cA; off = oA; cur = uA; nbk = nbkA; }
  else                 { cnt = cB; off = oB; cur = uB; nbk = nbkB; }
  int t = threadIdx.x;
  int v = (t < nbk) ? cnt[t] : 0;
  s[t] = v;
  __syncthreads();
  for (int o = 1; o < 512; o <<= 1) {
    int x = (t >= o) ? s[t - o] : 0;
    __syncthreads();
    s[t] += x;
    __syncthreads();
  }
  if (t < nbk) { int ex = s[t] - v; off[t] = ex; cur[t] = ex; }
  if (t == nbk - 1) off[nbk] = s[t];
}

__global__ void multisplit_kernel(const int* __restrict__ sA, const int* __restrict__ dA,
                                  int* __restrict__ uA, uint2* __restrict__ seA, int nbkA,
                                  const int* __restrict__ sB, const int* __restrict__ dB,
                                  int* __restrict__ uB, uint2* __restrict__ seB, int nbkB,
                                  int E, int chA) {
  __shared__ int cnt[NBK_MAX];
  __shared__ int base[NBK_MAX];
  int b = blockIdx.x;
  const int *src, *dst; int* gcur; uint2* se; int nbk;
  if (b < chA) { src = sA; dst = dA; gcur = uA; se = seA; nbk = nbkA; }
  else         { b -= chA; src = sB; dst = dB; gcur = uB; se = seB; nbk = nbkB; }
  for (int i = threadIdx.x; i < nbk; i += 256) cnt[i] = 0;
  __syncthreads();
  int e0 = b * 4096;
  int mys[16], myd[16], myb[16], myr[16];
#pragma unroll
  for (int j = 0; j < 16; ++j) {
    int e = e0 + j * 256 + threadIdx.x;
    int s = 0, d = 0, bb = -1, r = 0;
    if (e < E) {
      s = src[e]; d = dst[e];
      uint B = (uint)d >> BSH;
      if (B < (uint)nbk) { bb = (int)B; r = atomicAdd(&cnt[bb], 1); }
    }
    mys[j] = s; myd[j] = d; myb[j] = bb; myr[j] = r;
  }
  __syncthreads();
  for (int i = threadIdx.x; i < nbk; i += 256) {
    int c = cnt[i];
    base[i] = c ? atomicAdd(&gcur[i], c) : 0;
  }
  __syncthreads();
#pragma unroll
  for (int j = 0; j < 16; ++j) {
    if (myb[j] >= 0) {
      uint2 v; v.x = (uint)mys[j]; v.y = (uint)myd[j];
      se[base[myb[j]] + myr[j]] = v;
    }
  }
}

__global__ void csr_fine_kernel(const uint2* __restrict__ seA, const int* __restrict__ boA,
                                int* __restrict__ offA, int* __restrict__ csrA, int nA, int nbkA,
                                const uint2* __restrict__ seB, const int* __restrict__ boB,
                                int* __restrict__ offB, int* __restrict__ csrB, int nB) {
  __shared__ int s[256];
  __shared__ int cur[256];
  int b = blockIdx.x;
  const uint2* se; const int* bo; int* off; int* csr; int n;
  if (b < nbkA) { se = seA; bo = boA; off = offA; csr = csrA; n = nA; }
  else          { b -= nbkA; se = seB; bo = boB; off = offB; csr = csrB; n = nB; }
  int t = threadIdx.x;
  int ebeg = bo[b], eend = bo[b + 1];
  cur[t] = 0;
  __syncthreads();
  for (int i = ebeg + t; i < eend; i += 256)
    atomicAdd(&cur[se[i].y & 255], 1);
  __syncthreads();
  int v = cur[t];
  s[t] = v;
  __syncthreads();
  for (int o = 1; o < 256; o <<= 1) {
    int x = (t >= o) ? s[t - o] : 0;
    __syncthreads();
    s[t] += x;
    __syncthreads();
  }
  int excl = s[t] - v;
  int node = b * 256 + t;
  if (node < n) off[node] = ebeg + excl;
  if (node == n - 1) off[n] = ebeg + excl + v;
  cur[t] = excl;
  __syncthreads();
  for (int i = ebeg + t; i < eend; i += 256) {
    uint2 e = se[i];
    int pos = ebeg + atomicAdd(&cur[e.y & 255], 1);
    csr[pos] = (int)e.x;
  }
}

// ======================= pull aggregation (mean, bf16 out) ===================
// R7 VALU slim: the emitted loop was ~4x fatter than the required math
// (64-bit addr chains + scalar adds). Now: per-lane byte base hoisted, per-edge
// offset = s << log2(rowbytes) (one v_lshlrev), float2 accumulators -> LLVM
// emits v_pk_add_f32 (2 IEEE f32 adds/instr, same values/order =>
// bit-identical results). Element e lives in a[e/2].{x,y} matching old a[e].
__device__ __forceinline__ void accp8(float2v* a, uint4 v) {
  a[0] += (float2v){lo2f(v.x), hi2f(v.x)};
  a[1] += (float2v){lo2f(v.y), hi2f(v.y)};
  a[2] += (float2v){lo2f(v.z), hi2f(v.z)};
  a[3] += (float2v){lo2f(v.w), hi2f(v.w)};
}
__device__ __forceinline__ void accp4(float2v* a, float4 v) {
  a[0] += (float2v){v.x, v.y};
  a[1] += (float2v){v.z, v.w};
}

template <int D, bool XBF>
__device__ __forceinline__ void pull_worker(
    const int* __restrict__ off, const int* __restrict__ csr,
    const void* __restrict__ x, bf16* __restrict__ mean, int n, int nsrc,
    int blk0) {
  constexpr int EPL = XBF ? 8 : 4;           // elems per lane (16B either way)
  constexpr int LPR = D / EPL;               // lanes per row
  constexpr int PAR = 64 / LPR;              // edges in parallel
  constexpr int NP = EPL / 2;                // float2 accumulators
  constexpr uint RS = (uint)D * (XBF ? 2u : 4u);  // row bytes (pow2: 128/256)
  int node = ((int)blockIdx.x - blk0) * 4 + (threadIdx.x >> 6);
  if (node >= n) return;  // wave-uniform
  int lane = threadIdx.x & 63;
  int h = lane / LPR, col = lane % LPR;
  int beg = off[node], deg = off[node + 1] - beg;
  float inv = 1.0f / fmaxf((float)deg, 1.0f);
  const char* xb = (const char*)x + col * 16;  // lane-fixed byte base
  float2v a[NP];
#pragma unroll
  for (int e = 0; e < NP; ++e) a[e] = (float2v){0.f, 0.f};

  int i = h;
  // main loop: 4 edge-rounds in flight (R3-validated)
  for (; i + 3 * PAR < deg; i += 4 * PAR) {
    int s0 = csr[beg + i];
    int s1 = csr[beg + i + PAR];
    int s2 = csr[beg + i + 2 * PAR];
    int s3 = csr[beg + i + 3 * PAR];
    s0 = ((unsigned)s0 < (unsigned)nsrc) ? s0 : 0;
    s1 = ((unsigned)s1 < (unsigned)nsrc) ? s1 : 0;
    s2 = ((unsigned)s2 < (unsigned)nsrc) ? s2 : 0;
    s3 = ((unsigned)s3 < (unsigned)nsrc) ? s3 : 0;
    const char* p0 = xb + (uint)s0 * RS;
    const char* p1 = xb + (uint)s1 * RS;
    const char* p2 = xb + (uint)s2 * RS;
    const char* p3 = xb + (uint)s3 * RS;
    if (XBF) {
      uint4 v0 = *(const uint4*)p0;
      uint4 v1 = *(const uint4*)p1;
      uint4 v2 = *(const uint4*)p2;
      uint4 v3 = *(const uint4*)p3;
      accp8(a, v0); accp8(a, v1); accp8(a, v2); accp8(a, v3);
    } else {
      float4 v0 = *(const float4*)p0;
      float4 v1 = *(const float4*)p1;
      float4 v2 = *(const float4*)p2;
      float4 v3 = *(const float4*)p3;
      accp4(a, v0); accp4(a, v1); accp4(a, v2); accp4(a, v3);
    }
  }
  // tail
  for (; i < deg; i += PAR) {
    int s = csr[beg + i];
    s = ((unsigned)s < (unsigned)nsrc) ? s : 0;
    const char* p = xb + (uint)s * RS;
    if (XBF) {
      uint4 v = *(const uint4*)p;
      accp8(a, v);
    } else {
      float4 v = *(const float4*)p;
      accp4(a, v);
    }
  }

#pragma unroll
  for (int m = LPR; m < 64; m <<= 1) {
#pragma unroll
    for (int e = 0; e < NP; ++e) {
      a[e].x += __shfl_xor(a[e].x, m);
      a[e].y += __shfl_xor(a[e].y, m);
    }
  }
  if (h == 0) {
    if (XBF) {
      uint4 o4;
      o4.x = packbf2(a[0].x * inv, a[0].y * inv);
      o4.y = packbf2(a[1].x * inv, a[1].y * inv);
      o4.z = packbf2(a[2].x * inv, a[2].y * inv);
      o4.w = packbf2(a[3].x * inv, a[3].y * inv);
      ((uint4*)mean)[(long long)node * LPR + col] = o4;
    } else {
      uint2 o2;
      o2.x = packbf2(a[0].x * inv, a[0].y * inv);
      o2.y = packbf2(a[1].x * inv, a[1].y * inv);
      ((uint2*)mean)[(long long)node * LPR + col] = o2;
    }
  }
}

template <int DA, bool XA, int DB, bool XB>
__global__ __launch_bounds__(256) void pull2_kernel(
    const int* __restrict__ offA, const int* __restrict__ csrA,
    const void* __restrict__ xA, bf16* __restrict__ meanA, int nA, int nsrcA,
    const int* __restrict__ offB, const int* __restrict__ csrB,
    const void* __restrict__ xB, bf16* __restrict__ meanB, int nB, int nsrcB,
    int nblkA) {
  if ((int)blockIdx.x < nblkA)
    pull_worker<DA, XA>(offA, csrA, xA, meanA, nA, nsrcA, 0);
  else
    pull_worker<DB, XB>(offB, csrB, xB, meanB, nB, nsrcB, nblkA);
}

// ======================= MFMA GEMM worker (no LDS, MT row-tiles) =============
#define AT_BF16 0
#define AT_F32  1
template <int KT, int NCT, int K0T, int A0T, int A1T, bool OUTF32, int MT>
__device__ __forceinline__ void gemm_worker(
    const void* __restrict__ A0, int lda0,
    const void* __restrict__ A1, int lda1,
    const ushort* __restrict__ Wt, const float* __restrict__ bias,
    void* __restrict__ C, long long cbase, int ldc, int n, int relu, int blk0) {
  constexpr int K = KT * 32;
  int tid = threadIdx.x;
  int wave = tid >> 6, lane = tid & 63;
  int p = lane & 15, q = lane >> 4;
  int rowbase = ((int)blockIdx.x - blk0) * (64 * MT) + wave * (16 * MT);

  int rcl[MT];
#pragma unroll
  for (int m = 0; m < MT; ++m) rcl[m] = min(rowbase + m * 16 + p, n - 1);

  float4v acc[MT][NCT];
#pragma unroll
  for (int m = 0; m < MT; ++m)
#pragma unroll
    for (int t = 0; t < NCT; ++t) acc[m][t] = (float4v){0.f, 0.f, 0.f, 0.f};

#pragma unroll
  for (int kt = 0; kt < KT; ++kt) {
    const bool seg0 = (kt < K0T);
    const void* ab = seg0 ? A0 : A1;
    const int lda = seg0 ? lda0 : lda1;
    const int kof = (seg0 ? kt : (kt - K0T)) * 32;
    const int at = seg0 ? A0T : A1T;
    short8 af[MT];
#pragma unroll
    for (int m = 0; m < MT; ++m) {
      long long base = (long long)rcl[m] * lda + kof + q * 8;
      if (at == AT_BF16) {
        af[m] = *(const short8*)((const bf16*)ab + base);
      } else {
        const float* fb = (const float*)ab + base;
        float4 a = *(const float4*)fb;
        float4 b = *(const float4*)(fb + 4);
        short8 r;
        r[0] = (short)f2bu(a.x); r[1] = (short)f2bu(a.y);
        r[2] = (short)f2bu(a.z); r[3] = (short)f2bu(a.w);
        r[4] = (short)f2bu(b.x); r[5] = (short)f2bu(b.y);
        r[6] = (short)f2bu(b.z); r[7] = (short)f2bu(b.w);
        af[m] = r;
      }
    }
#pragma unroll
    for (int t = 0; t < NCT; ++t) {
      int c = t * 16 + p;
      short8 bfr = *(const short8*)(Wt + (long long)c * K + kt * 32 + q * 8);
#pragma unroll
      for (int m = 0; m < MT; ++m)
        acc[m][t] = __builtin_amdgcn_mfma_f32_16x16x32_bf16(af[m], bfr, acc[m][t], 0, 0, 0);
    }
  }

#pragma unroll
  for (int m = 0; m < MT; ++m) {
#pragma unroll
    for (int t = 0; t < NCT; ++t) {
      int c = t * 16 + p;
      float bv = bias[c];
#pragma unroll
      for (int r = 0; r < 4; ++r) {
        int row = rowbase + m * 16 + q * 4 + r;
        if (row < n) {
          float v = acc[m][t][r] + bv;
          if (relu) v = fmaxf(v, 0.f);
          long long idx = cbase + (long long)row * ldc + c;
          if (OUTF32) ((float*)C)[idx] = v;
          else        ((bf16*)C)[idx] = __float2bfloat16(v);
        }
      }
    }
  }
}

// ======================= layer-1: both GEMMs in one launch ===================
__global__ __launch_bounds__(256, 2) void gemm_l1_kernel(
    const bf16* __restrict__ m1ct, const float* __restrict__ xtxn,
    const ushort* __restrict__ Wt1, const float* __restrict__ b1ct,
    bf16* __restrict__ htxn,
    const bf16* __restrict__ m1tc, const float* __restrict__ xcli,
    const ushort* __restrict__ Wt2, const float* __restrict__ b1tc,
    bf16* __restrict__ hcli, int nT, int nC, int nblkA) {
  if ((int)blockIdx.x < nblkA)
    gemm_worker<3, 8, 1, AT_BF16, AT_F32, false, 4>(
        m1ct, 32, xtxn, 64, Wt1, b1ct, htxn, 0, 128, nT, 1, 0);
  else
    gemm_worker<3, 8, 2, AT_BF16, AT_F32, false, 4>(
        m1tc, 64, xcli, 32, Wt2, b1tc, hcli, 0, 128, nC, 1, nblkA);
}

// ======================= fused L2-txn GEMM + decoder worker (R6-validated) ===
__device__ __forceinline__ void dec_worker(
    char* zls,
    const bf16* __restrict__ A0,   // mean2_ct [n][128]
    const bf16* __restrict__ A1,   // h_txn    [n][128]
    const ushort* __restrict__ W3, // Wt3 [128][256]
    const float* __restrict__ b2,  // [128]
    const ushort* __restrict__ W5, // Wt5 [64][128]
    const float* __restrict__ bd1v,// [64]
    const ushort* __restrict__ W6, // Wt6 [64][64]
    const float* __restrict__ bd2v,// [64]
    float* __restrict__ zout,      // d_out + ztxn_base, ld 128
    float* __restrict__ recon,     // d_out, ld 64
    int n) {
  int tid = threadIdx.x;
  int wave = tid >> 6, lane = tid & 63;
  int p = lane & 15, q = lane >> 4;
  int rowbase = blockIdx.x * 256 + wave * 64;
  char* wls = zls + wave * 16384;
  const int sw = (p & 7) << 4;  // XOR swizzle

  // ---- stage Wt3 (64KB) into LDS, swizzled; all 4 waves cooperate ----
#pragma unroll
  for (int it = 0; it < 16; ++it) {
    int idx = it * 256 + tid;          // 16B granule, 4096 total
    int byte = idx << 4;
    int c = byte >> 9;                 // 512 B per weight column
    uint4 v = ((const uint4*)W3)[idx];
    *(uint4*)(zls + (byte ^ ((c & 7) << 4))) = v;
  }
  __syncthreads();

  int rcl[4];
#pragma unroll
  for (int m = 0; m < 4; ++m) rcl[m] = min(rowbase + m * 16 + p, n - 1);

  // ---- stage 1: z accumulators (transposed layout via swapped operands) ----
  float4v accz[4][8];
#pragma unroll
  for (int m = 0; m < 4; ++m)
#pragma unroll
    for (int t = 0; t < 8; ++t) accz[m][t] = (float4v){0.f, 0.f, 0.f, 0.f};

#pragma unroll
  for (int kt = 0; kt < 8; ++kt) {
    const bf16* ab = (kt < 4) ? A0 : A1;
    const int kof = (kt & 3) * 32;
    short8 af[4];
#pragma unroll
    for (int m = 0; m < 4; ++m)
      af[m] = *(const short8*)(ab + (long long)rcl[m] * 128 + kof + q * 8);
#pragma unroll
    for (int t = 0; t < 8; ++t) {
      int c = t * 16 + p;
      short8 bfr = *(const short8*)(zls + ((c * 512 + kt * 64 + q * 16) ^ ((c & 7) << 4)));
#pragma unroll
      for (int m = 0; m < 4; ++m)
        accz[m][t] = __builtin_amdgcn_mfma_f32_16x16x32_bf16(bfr, af[m], accz[m][t], 0, 0, 0);
    }
  }
  __syncthreads();  // all W3 reads done before z overwrites the LDS

  // epilogue: z -> global f32 (+bias), z -> LDS bf16 (row-major [64][256B], swz)
#pragma unroll
  for (int m = 0; m < 4; ++m) {
    int lr = m * 16 + p;
    int row = rowbase + lr;
#pragma unroll
    for (int t = 0; t < 8; ++t) {
      float4v bz = *(const float4v*)(b2 + t * 16 + q * 4);
      float4v v;
#pragma unroll
      for (int r = 0; r < 4; ++r) v[r] = accz[m][t][r] + bz[r];
      if (row < n)
        *(float4v*)(zout + (long long)row * 128 + t * 16 + q * 4) = v;
      uint2 u;
      u.x = packbf2(v[0], v[1]);
      u.y = packbf2(v[2], v[3]);
      *(uint2*)(wls + (((lr * 256 + t * 32 + q * 8)) ^ sw)) = u;
    }
  }
  __syncthreads();

  // ---- stage 2: d1 = relu(z @ Wd1 + bd1), K=128, 64 cols ----
  float4v accd[4][4];
#pragma unroll
  for (int m = 0; m < 4; ++m)
#pragma unroll
    for (int t = 0; t < 4; ++t) accd[m][t] = (float4v){0.f, 0.f, 0.f, 0.f};

#pragma unroll
  for (int kt2 = 0; kt2 < 4; ++kt2) {
    short8 zf[4];
#pragma unroll
    for (int m = 0; m < 4; ++m)
      zf[m] = *(const short8*)(wls + (((m * 16 + p) * 256 + kt2 * 64 + q * 16) ^ sw));
#pragma unroll
    for (int t2 = 0; t2 < 4; ++t2) {
      short8 wf = *(const short8*)(W5 + (long long)(t2 * 16 + p) * 128 + kt2 * 32 + q * 8);
#pragma unroll
      for (int m = 0; m < 4; ++m)
        accd[m][t2] = __builtin_amdgcn_mfma_f32_16x16x32_bf16(wf, zf[m], accd[m][t2], 0, 0, 0);
    }
  }
  __syncthreads();  // all z-reads done before overwriting region with d1

  // d1 (relu, bf16) -> LDS row-major [64][128B], same swizzle
#pragma unroll
  for (int m = 0; m < 4; ++m) {
    int lr = m * 16 + p;
#pragma unroll
    for (int t2 = 0; t2 < 4; ++t2) {
      float4v bb = *(const float4v*)(bd1v + t2 * 16 + q * 4);
      float4v v;
#pragma unroll
      for (int r = 0; r < 4; ++r) v[r] = fmaxf(accd[m][t2][r] + bb[r], 0.f);
      uint2 u;
      u.x = packbf2(v[0], v[1]);
      u.y = packbf2(v[2], v[3]);
      *(uint2*)(wls + (((lr * 128 + t2 * 32 + q * 8)) ^ sw)) = u;
    }
  }
  // same-wave LDS write->read is in-order; no barrier needed

  // ---- stage 3: recon = d1 @ Wd2 + bd2, K=64, 64 cols ----
  float4v accr[4][4];
#pragma unroll
  for (int m = 0; m < 4; ++m)
#pragma unroll
    for (int t = 0; t < 4; ++t) accr[m][t] = (float4v){0.f, 0.f, 0.f, 0.f};

#pragma unroll
  for (int kt3 = 0; kt3 < 2; ++kt3) {
    short8 df[4];
#pragma unroll
    for (int m = 0; m < 4; ++m)
      df[m] = *(const short8*)(wls + (((m * 16 + p) * 128 + kt3 * 64 + q * 16) ^ sw));
#pragma unroll
    for (int t3 = 0; t3 < 4; ++t3) {
      short8 wf = *(const short8*)(W6 + (long long)(t3 * 16 + p) * 64 + kt3 * 32 + q * 8);
#pragma unroll
      for (int m = 0; m < 4; ++m)
        accr[m][t3] = __builtin_amdgcn_mfma_f32_16x16x32_bf16(wf, df[m], accr[m][t3], 0, 0, 0);
    }
  }

#pragma unroll
  for (int m = 0; m < 4; ++m) {
    int row = rowbase + m * 16 + p;
    if (row < n) {
#pragma unroll
      for (int t3 = 0; t3 < 4; ++t3) {
        float4v bb = *(const float4v*)(bd2v + t3 * 16 + q * 4);
        float4v v;
#pragma unroll
        for (int r = 0; r < 4; ++r) v[r] = accr[m][t3][r] + bb[r];
        *(float4v*)(recon + (long long)row * 64 + t3 * 16 + q * 4) = v;
      }
    }
  }
}

// ======================= layer-2: fused-dec + cli GEMM in one launch =========
__global__ __launch_bounds__(256, 2) void dec_l2_kernel(
    const bf16* __restrict__ m2ct, const bf16* __restrict__ htxn,
    const ushort* __restrict__ W3, const float* __restrict__ b2ct,
    const ushort* __restrict__ W5, const float* __restrict__ bd1v,
    const ushort* __restrict__ W6, const float* __restrict__ bd2v,
    float* __restrict__ zout, float* __restrict__ recon,
    const bf16* __restrict__ m2tc, const bf16* __restrict__ hcli,
    const ushort* __restrict__ W4, const float* __restrict__ b2tc,
    float* __restrict__ outb, long long zcli_base,
    int nT, int nC, int nblkA) {
  __shared__ __align__(16) char zls[65536];  // dec branch: W3 stage, then z/d1
  if ((int)blockIdx.x < nblkA)
    dec_worker(zls, m2ct, htxn, W3, b2ct, W5, bd1v, W6, bd2v, zout, recon, nT);
  else
    gemm_worker<8, 8, 4, AT_BF16, AT_BF16, true, 4>(
        m2tc, 128, hcli, 128, W4, b2tc, outb, zcli_base, 128, nC, 0, nblkA);
}

// ======================= host ================================================
extern "C" void kernel_launch(void* const* d_in, const int* in_sizes, int n_in,
                              void* d_out, int out_size, void* d_ws,
                              size_t ws_size, hipStream_t stream) {
  const float* x_txn = (const float*)d_in[0];
  const float* x_cli = (const float*)d_in[1];
  const int* ct_src = (const int*)d_in[2];
  const int* ct_dst = (const int*)d_in[3];
  const int* tc_src = (const int*)d_in[4];
  const int* tc_dst = (const int*)d_in[5];
  const float* W1ctl = (const float*)d_in[6];
  const float* b1ct  = (const float*)d_in[7];
  const float* W1ctr = (const float*)d_in[8];
  const float* W1tcl = (const float*)d_in[9];
  const float* b1tc  = (const float*)d_in[10];
  const float* W1tcr = (const float*)d_in[11];
  const float* W2ctl = (const float*)d_in[12];
  const float* b2ct  = (const float*)d_in[13];
  const float* W2ctr = (const float*)d_in[14];
  const float* W2tcl = (const float*)d_in[15];
  const float* b2tc  = (const float*)d_in[16];
  const float* W2tcr = (const float*)d_in[17];
  const float* Wd1   = (const float*)d_in[18];
  const float* bd1   = (const float*)d_in[19];
  const float* Wd2   = (const float*)d_in[20];
  const float* bd2   = (const float*)d_in[21];

  const int E = in_sizes[2];  // 600000
  const int NT = 100000, NC = 20000;
  const int NBK_CT = (NT + 255) >> 8;  // 391
  const int NBK_TC = (NC + 255) >> 8;  // 79

  // ---- workspace carve ----
  size_t o = 0;
  auto carve = [&](size_t bytes) {
    void* p = (char*)d_ws + o;
    o = (o + bytes + 255) & ~(size_t)255;
    return p;
  };
  int* bcnt_ct = (int*)carve((size_t)NBK_CT * 4);       // zeroed
  int* bcnt_tc = (int*)carve((size_t)NBK_TC * 4);       // zeroed (same page run)
  size_t zero_bytes = o;
  int* boff_ct = (int*)carve((size_t)(NBK_CT + 1) * 4);
  int* boff_tc = (int*)carve((size_t)(NBK_TC + 1) * 4);
  int* bcur_ct = (int*)carve((size_t)NBK_CT * 4);
  int* bcur_tc = (int*)carve((size_t)NBK_TC * 4);
  uint2* se_ct = (uint2*)carve((size_t)E * 8);
  uint2* se_tc = (uint2*)carve((size_t)E * 8);
  int* off_ct = (int*)carve((size_t)(NT + 1) * 4);
  int* off_tc = (int*)carve((size_t)(NC + 1) * 4);
  int* csr_ct = (int*)carve((size_t)E * 4);
  int* csr_tc = (int*)carve((size_t)E * 4);
  ushort* Wt1 = (ushort*)carve((size_t)96 * 128 * 2);
  ushort* Wt2 = (ushort*)carve((size_t)96 * 128 * 2);
  ushort* Wt3 = (ushort*)carve((size_t)256 * 128 * 2);
  ushort* Wt4 = (ushort*)carve((size_t)256 * 128 * 2);
  ushort* Wt5 = (ushort*)carve((size_t)128 * 64 * 2);
  ushort* Wt6 = (ushort*)carve((size_t)64 * 64 * 2);
  bf16* mean1_ct = (bf16*)carve((size_t)NT * 32 * 2);
  bf16* mean1_tc = (bf16*)carve((size_t)NC * 64 * 2);
  bf16* h_txn    = (bf16*)carve((size_t)NT * 128 * 2);
  bf16* h_cli    = (bf16*)carve((size_t)NC * 128 * 2);
  bf16* mean2_ct = (bf16*)carve((size_t)NT * 128 * 2);
  bf16* mean2_tc = (bf16*)carve((size_t)NC * 128 * 2);
  (void)ws_size;

  hipMemsetAsync(d_ws, 0, zero_bytes, stream);

  const int tb = 256;
  const int CH = (E + 4095) / 4096;  // 147 chunks per edge type

  // ---- fused transpose + bhist (1 launch; saves one gap) ----
  {
    TJobs js;
    auto blocks = [](int k, int ncol) { return (k * ncol + 255) / 256; };
    int boff = 0;
    auto setj = [&](int idx, const float* wl, const float* wr, ushort* dst,
                    int da, int k, int ncol) {
      js.j[idx] = TJob{wl, wr, dst, da, k, ncol, boff};
      boff += blocks(k, ncol);
    };
    setj(0, W1ctl, W1ctr, Wt1, 32, 96, 128);
    setj(1, W1tcl, W1tcr, Wt2, 64, 96, 128);
    setj(2, W2ctl, W2ctr, Wt3, 128, 256, 128);
    setj(3, W2tcl, W2tcr, Wt4, 128, 256, 128);
    setj(4, Wd1, Wd1, Wt5, 128, 128, 64);
    setj(5, Wd2, Wd2, Wt6, 64, 64, 64);
    tr_bhist_kernel<<<2 * CH + boff, tb, 0, stream>>>(
        js, ct_dst, bcnt_ct, NBK_CT, tc_dst, bcnt_tc, NBK_TC, E, CH);
  }

  // ---- CSR build: scan -> multisplit -> fine ----
  bscan_kernel<<<2, 512, 0, stream>>>(bcnt_ct, boff_ct, bcur_ct, NBK_CT,
                                      bcnt_tc, boff_tc, bcur_tc, NBK_TC);
  multisplit_kernel<<<2 * CH, tb, 0, stream>>>(
      ct_src, ct_dst, bcur_ct, se_ct, NBK_CT,
      tc_src, tc_dst, bcur_tc, se_tc, NBK_TC, E, CH);
  csr_fine_kernel<<<NBK_CT + NBK_TC, tb, 0, stream>>>(
      se_ct, boff_ct, off_ct, csr_ct, NT, NBK_CT,
      se_tc, boff_tc, off_tc, csr_tc, NC);

  const int pbA = (NT + 3) / 4, pbB = (NC + 3) / 4;
  const int gA = (NT + 255) / 256;   // 391 (MT=4 / dec blocks)
  const int gB = (NC + 255) / 256;   // 79  (cli MT=4 blocks)

  // ---- layer 1: fused pull means, then both linears in one launch ----
  pull2_kernel<32, false, 64, false><<<pbA + pbB, tb, 0, stream>>>(
      off_ct, csr_ct, x_cli, mean1_ct, NT, NC,
      off_tc, csr_tc, x_txn, mean1_tc, NC, NT, pbA);

  gemm_l1_kernel<<<gA + gB, tb, 0, stream>>>(
      mean1_ct, x_txn, Wt1, b1ct, h_txn,
      mean1_tc, x_cli, Wt2, b1tc, h_cli, NT, NC, gA);

  // ---- layer 2: fused pull means ----
  pull2_kernel<128, true, 128, true><<<pbA + pbB, tb, 0, stream>>>(
      off_ct, csr_ct, h_cli, mean2_ct, NT, NC,
      off_tc, csr_tc, h_txn, mean2_tc, NC, NT, pbA);

  float* out = (float*)d_out;
  const long long ztxn_base = (long long)NT * 64;
  const long long zcli_base = ztxn_base + (long long)NT * 128;

  // ---- fused: (z_txn + decoder) blocks + z_cli GEMM blocks, one launch ----
  dec_l2_kernel<<<gA + gB, tb, 0, stream>>>(
      mean2_ct, h_txn, Wt3, b2ct, Wt5, bd1, Wt6, bd2,
      out + ztxn_base, out,
      mean2_tc, h_cli, Wt4, b2tc, out, zcli_base, NT, NC, gA);
}